// Round 6
// baseline (4886.039 us; speedup 1.0000x reference)
//
#include <hip/hip_runtime.h>
#include <hip/hip_bf16.h>
#include <math.h>

#define NN 10000
#define NE 160000
#define NG 64
#define NT 5
#define NL 4
#define ADL 2.833213344056216f
#define PQS 752               // PQ row stride (750 cols + 2 pad, keeps 8B alignment)

// ws layout (float offsets)
#define OFF_H      0
#define OFF_HC     750000
#define OFF_P      1500000     // bf16 PQ[10000][752] during agg; reused as bf16 post partials z=0..6
#define OFF_AGG    9000000     // bf16 agg (15M bf16 = 7.5M floats, ends 16.5M)
#define OFF_RLUT4  16500000    // 4 layers x 6000 floats
#define OFF_INVDEG 24006000
#define OFF_AMP    24016000
#define OFF_ATT    24026000
#define OFF_STATS  24036000    // 2 ping-pong buffers x 192 floats
#define OFF_GPOOL  24040000
#define OFF_INT    24118960

typedef __attribute__((ext_vector_type(2))) unsigned int uv2;

__device__ __forceinline__ float bf2f(__hip_bfloat16 v){ return __bfloat162float(v); }

// R22: manual RNE f32->bf16 pack, PURE register ops. R5's
// `unsigned short* ps = (unsigned short*)&pack` address-taken local defeated
// SROA -> pack went to SCRATCH -> 2.2 GB/dispatch of private-segment RMW
// traffic (FETCH 1.23GB, VALUBusy 3.8%). Never type-pun through a pointer to
// a local. Bit-identical to __float2bfloat16 for all finite values.
__device__ __forceinline__ unsigned int pack2bf(float a, float b){
    unsigned int ua = __float_as_uint(a);
    unsigned int ub = __float_as_uint(b);
    ua = (ua + (0x7fffu + ((ua >> 16) & 1u))) >> 16;
    ub =  ub + (0x7fffu + ((ub >> 16) & 1u));
    return (ua & 0xffffu) | (ub & 0xffff0000u);
}

__global__ void k_zero_cnt(int* cnt){
    int i = blockIdx.x*256 + threadIdx.x;
    if (i < NN) cnt[i] = 0;
}

// h0 = node_emb[x].reshape(N,150) @ pre_lin_W + b
__global__ __launch_bounds__(256) void k_h0(const int* __restrict__ x,
        const float* __restrict__ node_emb, const float* __restrict__ plW,
        const float* __restrict__ plb, float* __restrict__ h){
    __shared__ float s_emb[21*75];
    __shared__ float s_W[150*75];
    __shared__ float s_b[75];
    int tid = threadIdx.x;
    for (int i = tid; i < 21*75; i += 256) s_emb[i] = node_emb[i];
    for (int i = tid; i < 150*75; i += 256) s_W[i] = plW[i];
    if (tid < 75) s_b[tid] = plb[tid];
    __syncthreads();
    for (int out = blockIdx.x*256 + tid; out < NN*75; out += gridDim.x*256){
        int n = out / 75, f = out - n*75;
        int x0 = x[2*n], x1 = x[2*n+1];
        float acc = s_b[f];
        const float* e0 = s_emb + x0*75;
        const float* e1 = s_emb + x1*75;
        #pragma unroll 5
        for (int k = 0; k < 75; k++)
            acc += e0[k]*s_W[k*75+f] + e1[k]*s_W[(75+k)*75+f];
        h[out] = acc;
    }
}

__global__ void k_hist(const int* __restrict__ ei, int* __restrict__ cnt){
    int e = blockIdx.x*256 + threadIdx.x;
    if (e < NE) atomicAdd(&cnt[ei[NE + e]], 1);
}

// single-block prefix sum: eoff[0]=0, eoff[n+1]=inclusive prefix
__global__ void k_scan(const int* __restrict__ cnt, int* __restrict__ eoff){
    __shared__ int buf[256];
    __shared__ int carry;
    int tid = threadIdx.x;
    if (tid == 0){ carry = 0; eoff[0] = 0; }
    __syncthreads();
    for (int base = 0; base < NN; base += 256){
        int v = (base + tid < NN) ? cnt[base + tid] : 0;
        buf[tid] = v; __syncthreads();
        for (int off = 1; off < 256; off <<= 1){
            int t2 = (tid >= off) ? buf[tid - off] : 0;
            __syncthreads();
            buf[tid] += t2;
            __syncthreads();
        }
        int inc = buf[tid] + carry;
        if (base + tid < NN) eoff[base + tid + 1] = inc;
        __syncthreads();
        if (tid == 255) carry = inc;
        __syncthreads();
    }
}

__global__ void k_nodestats(const int* __restrict__ cnt, const int* __restrict__ eoff,
        float* __restrict__ invdeg, float* __restrict__ amp, float* __restrict__ att,
        int* __restrict__ cursor){
    int n = blockIdx.x*256 + threadIdx.x;
    if (n >= NN) return;
    int c = cnt[n];
    cursor[n] = eoff[n];
    float cf = (float)c;
    float dg = cf < 1.f ? 1.f : cf;
    invdeg[n] = 1.f / dg;
    float ld = logf(dg + 1.f);
    amp[n] = ld / ADL;
    att[n] = ADL / ld;
}

__global__ void k_scatter(const int* __restrict__ ei, const int* __restrict__ ea,
        int* __restrict__ cursor, int* __restrict__ esrc, int* __restrict__ ecombo){
    int e = blockIdx.x*256 + threadIdx.x;
    if (e >= NE) return;
    int src = ei[e], dst = ei[NE + e];
    int pos = atomicAdd(&cursor[dst], 1);
    esrc[pos] = src;
    ecombo[pos] = ea[2*e]*4 + ea[2*e+1];
}

// R19: Rlut depends only on weights -> hoisted out of the layer loop.
// One launch, grid (5 towers, 4 layers).
__global__ __launch_bounds__(384) void k_rlut4(
        const float* __restrict__ preW, const float* __restrict__ preb,
        const float* __restrict__ edge_emb, const float* __restrict__ encW,
        const float* __restrict__ encb, float* __restrict__ rlut_all){
    __shared__ float smem[10675];
    int tid = threadIdx.x;
    int t = blockIdx.x;
    int l = blockIdx.y;
    float* s_encW = smem;            // 50*75 = 3750
    float* s_ev   = smem + 3750;     // 16*75 = 1200
    float* s_wc   = smem + 4950;     // 75*75 = 5625
    float* s_ee   = smem + 10575;    // 100
    for (int i = tid; i < 3750; i += 384) s_encW[i] = encW[(size_t)l*3750 + i];
    for (int i = tid; i < 100; i += 384) s_ee[i] = edge_emb[i];
    const float* wcsrc = preW + (((size_t)(l*NT + t))*225 + 150)*75;
    for (int i = tid; i < 5625; i += 384) s_wc[i] = wcsrc[i];
    __syncthreads();
    for (int task = tid; task < 1200; task += 384){
        int b = task/75, m = task - 75*b;
        int a0 = b >> 2, a1 = b & 3;
        float s = encb[l*75 + m];
        for (int k = 0; k < 25; k++)
            s += s_ee[a0*25+k]*s_encW[k*75+m] + s_ee[a1*25+k]*s_encW[(25+k)*75+m];
        s_ev[task] = s;
    }
    __syncthreads();
    for (int task = tid; task < 1200; task += 384){
        int b = task/75, f = task - 75*b;
        float r = preb[((size_t)l*NT + t)*75 + f];
        const float* ev = s_ev + b*75;
        #pragma unroll 5
        for (int m = 0; m < 75; m++) r += ev[m]*s_wc[m*75 + f];
        rlut_all[(size_t)l*6000 + b*375 + t*75 + f] = r;
    }
}

// R20/R21/R22: k_pq = LDS-tiled GEMM C[10000x750] = h[10000x75] @ Wc[75x750].
// R21a: XCD-chunked bijective block swizzle (T1) - each XCD owns consecutive
// node-tiles x all 12 col-tiles so h/hc re-reads hit its own L2.
// R21b: merged PQ[n][752] output, 8B packed stores.
// R22: pack built with integer ops in registers (see pack2bf; R5 scratch bug).
__global__ __launch_bounds__(256, 4) void k_pq(float* __restrict__ h,
        const float* __restrict__ hc, const float* __restrict__ bng,
        const float* __restrict__ bnb,
        const float* __restrict__ preW,
        int l, __hip_bfloat16* __restrict__ PQ,
        const float* __restrict__ stats_all){
    __shared__ float s_h[64*76];   // node-major, col 75 = 0 pad
    __shared__ float s_w[76*64];   // k-major, row 75 = 0 pad
    int tid = threadIdx.x;

    // bijective XCD-chunk remap: bid -> A, node-major within each XCD
    int bid = blockIdx.x;                 // 0..1883
    const int qq = 1884 >> 3;             // 235
    const int rr = 1884 & 7;              // 4
    int xcd = bid & 7, ii = bid >> 3;
    int A = (xcd < rr) ? xcd*(qq+1) + ii : rr*(qq+1) + (xcd - rr)*qq + ii;
    int tile_n = A / 12;                  // 0..156
    int tile_c = A - tile_n*12;           // 0..11
    int base_n = tile_n*64;
    int base_c = tile_c*64;
    int tx = tid & 15;             // col group (4 cols)
    int ty = tid >> 4;             // node group (4 nodes)

    // stage h tile (l>0: BN+ReLU from previous layer, write-back once)
    if (l == 0){
        for (int idx = tid; idx < 64*76; idx += 256){
            int i = idx/76, m = idx - 76*i;
            int n = base_n + i;
            s_h[idx] = (m < 75 && n < NN) ? h[(size_t)n*75 + m] : 0.f;
        }
    } else {
        const float* stats_rd = stats_all + ((l + 1) & 1)*192;
        int lp = l - 1;
        for (int idx = tid; idx < 64*76; idx += 256){
            int i = idx/76, m = idx - 76*i;
            int n = base_n + i;
            float v = 0.f;
            if (m < 75 && n < NN){
                float mu = stats_rd[m]*(1.0f/NN);
                float var = stats_rd[75+m]*(1.0f/NN) - mu*mu;
                float inv = rsqrtf(var + 1e-5f);
                v = (hc[(size_t)n*75 + m] - mu)*inv*bng[lp*75+m] + bnb[lp*75+m];
                v = v > 0.f ? v : 0.f;
                if (tile_c == 0) h[(size_t)n*75 + m] = v;
            }
            s_h[idx] = v;
        }
    }
    // stage W tile: k-major, wave lanes cover 64 consecutive cols -> coalesced
    for (int idx = tid; idx < 76*64; idx += 256){
        int k = idx >> 6, c = idx & 63;
        int col = base_c + c;
        float v = 0.f;
        if (k < 75 && col < 750){
            int cc2 = col < 375 ? col : col - 375;
            int t = cc2/75, f = cc2 - t*75;
            int ro = col < 375 ? 0 : 75;
            v = preW[(((size_t)(l*NT + t))*225 + ro + k)*75 + f];
        }
        s_w[idx] = v;
    }
    __syncthreads();

    float acc[4][4] = {};
    const float* hrow = s_h + (ty*4)*76;
    const float* wrow = s_w + tx*4;
    for (int k4 = 0; k4 < 76; k4 += 4){
        float4 hv[4], wv[4];
        #pragma unroll
        for (int r = 0; r < 4; r++)
            hv[r] = *(const float4*)(hrow + r*76 + k4);
        #pragma unroll
        for (int kk = 0; kk < 4; kk++)
            wv[kk] = *(const float4*)(wrow + (k4+kk)*64);
        #pragma unroll
        for (int r = 0; r < 4; r++){
            float h0 = hv[r].x, h1 = hv[r].y, h2 = hv[r].z, h3 = hv[r].w;
            acc[r][0] += h0*wv[0].x + h1*wv[1].x + h2*wv[2].x + h3*wv[3].x;
            acc[r][1] += h0*wv[0].y + h1*wv[1].y + h2*wv[2].y + h3*wv[3].y;
            acc[r][2] += h0*wv[0].z + h1*wv[1].z + h2*wv[2].z + h3*wv[3].z;
            acc[r][3] += h0*wv[0].w + h1*wv[1].w + h2*wv[2].w + h3*wv[3].w;
        }
    }

    int c0 = base_c + tx*4;
    if (c0 >= 750) return;     // fully out-of-range threads (tile 11 only)
    #pragma unroll
    for (int r = 0; r < 4; r++){
        int n = base_n + ty*4 + r;
        if (n >= NN) continue;
        // c0 <= 748: a 4-pack may spill into pad cols 750/751 (never read)
        uv2 pk;
        pk.x = pack2bf(acc[r][0], acc[r][1]);
        pk.y = pack2bf(acc[r][2], acc[r][3]);
        *(uv2*)&PQ[(size_t)n*PQS + c0] = pk;
    }
}

// grid (6, NN), block 64. bf16 Q gather; edge loop unrolled x8.
// R20: block (0,0) additionally zeros the BN-stats buffer for this layer.
// R21: reads merged PQ buffer (P = cols 0..374, Q = cols 375..749).
__global__ __launch_bounds__(64) void k_agg(const __hip_bfloat16* __restrict__ PQ,
        const float* __restrict__ Rlut,
        const int* __restrict__ eoff, const int* __restrict__ esrc,
        const int* __restrict__ ecombo, const float* __restrict__ invdeg,
        __hip_bfloat16* __restrict__ agg, float* __restrict__ stats_zero){
    int n = blockIdx.y;
    int j = blockIdx.x*64 + threadIdx.x;
    if (blockIdx.x == 0 && n == 0){
        for (int i = threadIdx.x; i < 150; i += 64) stats_zero[i] = 0.f;
    }
    if (j >= 375) return;
    int lo = eoff[n], hi = eoff[n+1];
    float p = bf2f(PQ[(size_t)n*PQS + j]);
    const __hip_bfloat16* Qb = PQ + 375;
    float sum = 0.f, sq = 0.f, mn = 3.4e38f, mx = -3.4e38f;
    int e = lo;
    for (; e + 8 <= hi; e += 8){
        int s0 = esrc[e],   s1 = esrc[e+1], s2 = esrc[e+2], s3 = esrc[e+3];
        int s4 = esrc[e+4], s5 = esrc[e+5], s6 = esrc[e+6], s7 = esrc[e+7];
        int c0 = ecombo[e],   c1 = ecombo[e+1], c2 = ecombo[e+2], c3 = ecombo[e+3];
        int c4 = ecombo[e+4], c5 = ecombo[e+5], c6 = ecombo[e+6], c7 = ecombo[e+7];
        float q0 = bf2f(Qb[(size_t)s0*PQS + j]);
        float q1 = bf2f(Qb[(size_t)s1*PQS + j]);
        float q2 = bf2f(Qb[(size_t)s2*PQS + j]);
        float q3 = bf2f(Qb[(size_t)s3*PQS + j]);
        float q4 = bf2f(Qb[(size_t)s4*PQS + j]);
        float q5 = bf2f(Qb[(size_t)s5*PQS + j]);
        float q6 = bf2f(Qb[(size_t)s6*PQS + j]);
        float q7 = bf2f(Qb[(size_t)s7*PQS + j]);
        float r0 = Rlut[c0*375 + j], r1 = Rlut[c1*375 + j];
        float r2 = Rlut[c2*375 + j], r3 = Rlut[c3*375 + j];
        float r4 = Rlut[c4*375 + j], r5 = Rlut[c5*375 + j];
        float r6 = Rlut[c6*375 + j], r7 = Rlut[c7*375 + j];
        float m0 = p + q0 + r0, m1 = p + q1 + r1;
        float m2 = p + q2 + r2, m3 = p + q3 + r3;
        float m4 = p + q4 + r4, m5 = p + q5 + r5;
        float m6 = p + q6 + r6, m7 = p + q7 + r7;
        sum += (m0 + m1 + m2 + m3) + (m4 + m5 + m6 + m7);
        sq  += (m0*m0 + m1*m1 + m2*m2 + m3*m3) + (m4*m4 + m5*m5 + m6*m6 + m7*m7);
        mn = fminf(mn, fminf(fminf(fminf(m0,m1), fminf(m2,m3)),
                             fminf(fminf(m4,m5), fminf(m6,m7))));
        mx = fmaxf(mx, fmaxf(fmaxf(fmaxf(m0,m1), fmaxf(m2,m3)),
                             fmaxf(fmaxf(m4,m5), fmaxf(m6,m7))));
    }
    for (; e < hi; e++){
        int s = esrc[e], cm = ecombo[e];
        float m = p + bf2f(Qb[(size_t)s*PQS + j]) + Rlut[cm*375 + j];
        sum += m; sq += m*m;
        mn = fminf(mn, m); mx = fmaxf(mx, m);
    }
    float id = invdeg[n];
    bool has = hi > lo;
    float mean = sum*id;
    float msq  = sq*id;
    float var = msq - mean*mean; var = var > 0.f ? var : 0.f;
    float sd = sqrtf(var + 1e-5f);
    float mnv = has ? mn : 0.f;
    float mxv = has ? mx : 0.f;
    int t = j/75, f = j - 75*t;
    __hip_bfloat16* a = agg + ((size_t)n*NT + t)*300;
    a[f]      = __float2bfloat16(mean);
    a[75+f]   = __float2bfloat16(mnv);
    a[150+f]  = __float2bfloat16(mxv);
    a[225+f]  = __float2bfloat16(sd);
}

// post einsum, barrier-free; bf16 partials. grid (79, 5, 7).
// R19: 128-node tile: LDS 22.9 KB, 2765 blocks for smoother CU packing.
// R17 LDS staging retained: agg tile stride 52 ushorts, conflict-free.
#define KB2 50
__global__ __launch_bounds__(256, 6) void k_post(const float* __restrict__ h,
        const __hip_bfloat16* __restrict__ agg, const float* __restrict__ postW,
        const float* __restrict__ postb, const float* __restrict__ amp,
        const float* __restrict__ att, int l, __hip_bfloat16* __restrict__ postbase){
    __shared__ float s_w[3*KB2*16];              // 9.6 KB (z0 uses first 75*16=1200)
    __shared__ unsigned short s_a[128*52];       // 13.3 KB agg tile
    int t = blockIdx.y;
    int z = blockIdx.z;
    int nbase = blockIdx.x*128;
    int tid = threadIdx.x;
    int fg  = (tid & 3)*4;
    int sub = tid >> 2;
    const float* Wt = postW + ((size_t)(l*NT + t))*975*15;

    if (z == 0){
        for (int idx = tid; idx < 75*16; idx += 256){
            int c = idx >> 4, f = idx & 15;
            s_w[idx] = (f < 15) ? Wt[c*15 + f] : 0.f;
        }
        __syncthreads();
        float a1[2][4] = {};
        const float* hrow[2];
        #pragma unroll
        for (int j = 0; j < 2; j++){
            int n = nbase + sub + 64*j;
            hrow[j] = h + (size_t)(n < NN ? n : 0)*75;
        }
        #pragma unroll 3
        for (int k = 0; k < 75; k++){
            const float4 w1 = *(const float4*)&s_w[k*16 + fg];
            #pragma unroll
            for (int j = 0; j < 2; j++){
                float v = hrow[j][k];
                a1[j][0] += v*w1.x; a1[j][1] += v*w1.y;
                a1[j][2] += v*w1.z; a1[j][3] += v*w1.w;
            }
        }
        const float* pb = postb + (l*NT + t)*15;
        #pragma unroll
        for (int j = 0; j < 2; j++){
            int n = nbase + sub + 64*j;
            if (n >= NN) continue;
            __hip_bfloat16* dst = postbase + (size_t)n*75 + t*15;
            #pragma unroll
            for (int f = 0; f < 4; f++)
                if (fg + f < 15) dst[fg + f] = __float2bfloat16(a1[j][f] + pb[fg + f]);
        }
        return;
    }

    int kbeg = (z-1)*KB2;
    // stage weights
    for (int idx = tid; idx < 3*KB2*16; idx += 256){
        int vrow = idx / (KB2*16);
        int rem = idx - vrow*(KB2*16);
        int c = rem >> 4, f = rem & 15;
        s_w[idx] = (f < 15) ? Wt[(75 + vrow*300 + kbeg + c)*15 + f] : 0.f;
    }
    // stage agg tile: node i's 50 bf16 slice = 25 dwords, contiguous 100B runs
    {
        const unsigned short* asrc = (const unsigned short*)agg;
        for (int idx = tid; idx < 128*25; idx += 256){
            int i = idx/25, w = idx - 25*i;
            int n = nbase + i;
            unsigned int u = 0;
            if (n < NN)
                u = *(const unsigned int*)(asrc + (size_t)n*1500 + t*300 + kbeg + 2*w);
            *(unsigned int*)&s_a[i*52 + 2*w] = u;
        }
    }
    __syncthreads();

    float a1[2][4] = {}, a2[2][4] = {}, a3[2][4] = {};
    const unsigned short* ap0 = s_a + sub*52;
    #pragma unroll 2
    for (int k4 = 0; k4 < 48; k4 += 4){
        uv2 ua[2];
        #pragma unroll
        for (int j = 0; j < 2; j++)
            ua[j] = *(const uv2*)(ap0 + j*(64*52) + k4);
        #pragma unroll
        for (int kk = 0; kk < 4; kk++){
            int k = k4 + kk;
            const float4 w1 = *(const float4*)&s_w[k*16 + fg];
            const float4 w2 = *(const float4*)&s_w[(KB2 + k)*16 + fg];
            const float4 w3 = *(const float4*)&s_w[(2*KB2 + k)*16 + fg];
            #pragma unroll
            for (int j = 0; j < 2; j++){
                unsigned int bits = (kk < 2) ? ua[j].x : ua[j].y;
                float v = __uint_as_float((kk & 1) ? (bits & 0xffff0000u)
                                                   : (bits << 16));
                a1[j][0] += v*w1.x; a1[j][1] += v*w1.y;
                a1[j][2] += v*w1.z; a1[j][3] += v*w1.w;
                a2[j][0] += v*w2.x; a2[j][1] += v*w2.y;
                a2[j][2] += v*w2.z; a2[j][3] += v*w2.w;
                a3[j][0] += v*w3.x; a3[j][1] += v*w3.y;
                a3[j][2] += v*w3.z; a3[j][3] += v*w3.w;
            }
        }
    }
    // tail k = 48, 49 (one dword per row)
    {
        unsigned int ut[2];
        #pragma unroll
        for (int j = 0; j < 2; j++)
            ut[j] = *(const unsigned int*)(ap0 + j*(64*52) + 48);
        #pragma unroll
        for (int kk = 0; kk < 2; kk++){
            int k = 48 + kk;
            const float4 w1 = *(const float4*)&s_w[k*16 + fg];
            const float4 w2 = *(const float4*)&s_w[(KB2 + k)*16 + fg];
            const float4 w3 = *(const float4*)&s_w[(2*KB2 + k)*16 + fg];
            #pragma unroll
            for (int j = 0; j < 2; j++){
                float v = __uint_as_float((kk & 1) ? (ut[j] & 0xffff0000u)
                                                   : (ut[j] << 16));
                a1[j][0] += v*w1.x; a1[j][1] += v*w1.y;
                a1[j][2] += v*w1.z; a1[j][3] += v*w1.w;
                a2[j][0] += v*w2.x; a2[j][1] += v*w2.y;
                a2[j][2] += v*w2.z; a2[j][3] += v*w2.w;
                a3[j][0] += v*w3.x; a3[j][1] += v*w3.y;
                a3[j][2] += v*w3.z; a3[j][3] += v*w3.w;
            }
        }
    }
    __hip_bfloat16* postv = postbase + (size_t)z*750000;
    #pragma unroll
    for (int j = 0; j < 2; j++){
        int n = nbase + sub + 64*j;
        if (n >= NN) continue;
        float am = amp[n], at = att[n];
        __hip_bfloat16* dst = postv + (size_t)n*75 + t*15;
        #pragma unroll
        for (int f = 0; f < 4; f++)
            if (fg + f < 15)
                dst[fg + f] = __float2bfloat16(a1[j][f] + am*a2[j][f] + at*a3[j][f]);
    }
}

// hc = (Σz postz) @ lin_W[l] + lin_b[l]; fused BN-stat reduction into buffer l&1.
__global__ __launch_bounds__(256) void k_lin(const __hip_bfloat16* __restrict__ postbase,
        const float* __restrict__ linW, const float* __restrict__ linb,
        int l, float* __restrict__ hc, float* __restrict__ stats_all){
    __shared__ float p_l[32*75];
    __shared__ float w_l[75*75];
    __shared__ float hc_l[32*75];
    int tid = threadIdx.x;
    int base = blockIdx.x*32;
    for (int i = tid; i < 75*75; i += 256) w_l[i] = linW[(size_t)l*5625 + i];
    for (int i = tid; i < 32*75; i += 256){
        int n = base + i/75;
        size_t idx = (size_t)base*75 + i;
        float v = 0.f;
        if (n < NN){
            #pragma unroll
            for (int z = 0; z < 7; z++) v += bf2f(postbase[idx + (size_t)z*750000]);
        }
        p_l[i] = v;
    }
    __syncthreads();
    for (int task = tid; task < 2400; task += 256){
        int i = task/75, o = task - 75*i;
        float s = linb[l*75 + o];
        const float* pl = p_l + i*75;
        #pragma unroll 5
        for (int j = 0; j < 75; j++) s += pl[j]*w_l[j*75 + o];
        hc_l[task] = s;
        if (base + i < NN) hc[(size_t)(base+i)*75 + o] = s;
    }
    __syncthreads();
    if (tid < 75){
        float* stats_wr = stats_all + (l & 1)*192;
        int nv = NN - base; if (nv > 32) nv = 32;
        float s1 = 0.f, s2 = 0.f;
        for (int i = 0; i < nv; i++){
            float v = hc_l[i*75 + tid];
            s1 += v; s2 += v*v;
        }
        atomicAdd(&stats_wr[tid], s1);
        atomicAdd(&stats_wr[75+tid], s2);
    }
}

// final BN apply (only after last layer; earlier layers fused into k_pq)
__global__ void k_bnapply(const float* __restrict__ hc, const float* __restrict__ stats,
        const float* __restrict__ bng, const float* __restrict__ bnb, int l,
        float* __restrict__ h){
    int idx = blockIdx.x*256 + threadIdx.x;
    if (idx >= NN*75) return;
    int col = idx % 75;
    float mu = stats[col]*(1.0f/NN);
    float var = stats[75+col]*(1.0f/NN) - mu*mu;
    float inv = rsqrtf(var + 1e-5f);
    float v = (hc[idx] - mu)*inv*bng[l*75+col] + bnb[l*75+col];
    h[idx] = v > 0.f ? v : 0.f;
}

__global__ __launch_bounds__(256) void k_pool(const float* __restrict__ h,
        const int* __restrict__ batch, float* __restrict__ gpool){
    int g = blockIdx.x, tid = threadIdx.x;
    int lo = 0, hi = NN;
    while (lo < hi){ int mid = (lo+hi)>>1; if (batch[mid] < g) lo = mid+1; else hi = mid; }
    int start = lo;
    lo = start; hi = NN;
    while (lo < hi){ int mid = (lo+hi)>>1; if (batch[mid] < g+1) lo = mid+1; else hi = mid; }
    int end = lo;
    __shared__ float red[225];
    if (tid < 225){
        int col = tid % 75, rep = tid / 75;
        float acc = 0.f;
        for (int i = start + rep; i < end; i += 3) acc += h[(size_t)i*75 + col];
        red[tid] = acc;
    }
    __syncthreads();
    if (tid < 75) gpool[g*75 + tid] = red[tid] + red[75+tid] + red[150+tid];
}

// 8 blocks x 8 graphs; weights in LDS, phase-parallel
__global__ __launch_bounds__(256) void k_mlp(const float* __restrict__ gpool,
        const float* __restrict__ W1, const float* __restrict__ b1,
        const float* __restrict__ W2, const float* __restrict__ b2,
        const float* __restrict__ W3, const float* __restrict__ b3,
        float* __restrict__ out){
    __shared__ float w1[75*50];
    __shared__ float w2[50*25];
    __shared__ float gp[8*75];
    __shared__ float t1[8*50];
    __shared__ float t2[8*25];
    int tid = threadIdx.x;
    int gbase = blockIdx.x*8;
    for (int i = tid; i < 75*50; i += 256) w1[i] = W1[i];
    for (int i = tid; i < 50*25; i += 256) w2[i] = W2[i];
    for (int i = tid; i < 8*75; i += 256) gp[i] = gpool[gbase*75 + i];
    __syncthreads();
    for (int task = tid; task < 8*50; task += 256){
        int g = task/50, j = task - 50*g;
        float s = b1[j];
        const float* gv = gp + g*75;
        #pragma unroll 5
        for (int k = 0; k < 75; k++) s += gv[k]*w1[k*50+j];
        t1[task] = s > 0.f ? s : 0.f;
    }
    __syncthreads();
    for (int task = tid; task < 8*25; task += 256){
        int g = task/25, j = task - 25*g;
        float s = b2[j];
        const float* tv = t1 + g*50;
        #pragma unroll 5
        for (int k = 0; k < 50; k++) s += tv[k]*w2[k*25+j];
        t2[task] = s > 0.f ? s : 0.f;
    }
    __syncthreads();
    if (tid < 8){
        float s = b3[0];
        const float* tv = t2 + tid*25;
        #pragma unroll
        for (int k = 0; k < 25; k++) s += tv[k]*W3[k];
        out[gbase + tid] = s;
    }
}

extern "C" void kernel_launch(void* const* d_in, const int* in_sizes, int n_in,
                              void* d_out, int out_size, void* d_ws, size_t ws_size,
                              hipStream_t stream){
    const int* x          = (const int*)d_in[0];
    const int* edge_index = (const int*)d_in[1];
    const int* edge_attr  = (const int*)d_in[2];
    const int* batch      = (const int*)d_in[3];
    const float* node_emb = (const float*)d_in[4];
    const float* edge_emb = (const float*)d_in[5];
    const float* pre_lin_W= (const float*)d_in[6];
    const float* pre_lin_b= (const float*)d_in[7];
    const float* encW     = (const float*)d_in[8];
    const float* encb     = (const float*)d_in[9];
    const float* preW     = (const float*)d_in[10];
    const float* preb     = (const float*)d_in[11];
    const float* postW    = (const float*)d_in[12];
    const float* postb    = (const float*)d_in[13];
    const float* linW     = (const float*)d_in[14];
    const float* linb     = (const float*)d_in[15];
    const float* bng      = (const float*)d_in[16];
    const float* bnb      = (const float*)d_in[17];
    const float* mlpW1    = (const float*)d_in[18];
    const float* mlpb1    = (const float*)d_in[19];
    const float* mlpW2    = (const float*)d_in[20];
    const float* mlpb2    = (const float*)d_in[21];
    const float* mlpW3    = (const float*)d_in[22];
    const float* mlpb3    = (const float*)d_in[23];

    float* ws = (float*)d_ws;
    float* h      = ws + OFF_H;
    float* hc     = ws + OFF_HC;
    __hip_bfloat16* PQ = (__hip_bfloat16*)(ws + OFF_P);
    __hip_bfloat16* agg = (__hip_bfloat16*)(ws + OFF_AGG);
    float* rlut4  = ws + OFF_RLUT4;
    float* invdeg = ws + OFF_INVDEG;
    float* amp    = ws + OFF_AMP;
    float* att    = ws + OFF_ATT;
    float* stats  = ws + OFF_STATS;   // 2 x 192 ping-pong
    float* gpool  = ws + OFF_GPOOL;
    __hip_bfloat16* postbase = (__hip_bfloat16*)(ws + OFF_P);  // bf16 partials z=0..6
    int* iw     = (int*)(ws + OFF_INT);
    int* cnt    = iw;
    int* eoff   = cnt + NN;        // NN+1
    int* cursor = eoff + NN + 2;
    int* esrc   = cursor + NN;
    int* ecombo = esrc + NE;

    k_zero_cnt<<<40, 256, 0, stream>>>(cnt);
    k_rlut4<<<dim3(5, 4), 384, 0, stream>>>(preW, preb, edge_emb, encW, encb, rlut4);
    k_h0<<<640, 256, 0, stream>>>(x, node_emb, pre_lin_W, pre_lin_b, h);
    k_hist<<<625, 256, 0, stream>>>(edge_index, cnt);
    k_scan<<<1, 256, 0, stream>>>(cnt, eoff);
    k_nodestats<<<40, 256, 0, stream>>>(cnt, eoff, invdeg, amp, att, cursor);
    k_scatter<<<625, 256, 0, stream>>>(edge_index, edge_attr, cursor, esrc, ecombo);

    for (int l = 0; l < NL; l++){
        k_pq<<<1884, 256, 0, stream>>>(h, hc, bng, bnb, preW, l, PQ, stats);
        k_agg<<<dim3(6, NN), 64, 0, stream>>>(PQ, rlut4 + (size_t)l*6000,
                                              eoff, esrc, ecombo, invdeg, agg,
                                              stats + (l & 1)*192);
        k_post<<<dim3(79, 5, 7), 256, 0, stream>>>(h, agg, postW, postb, amp, att, l, postbase);
        k_lin<<<313, 256, 0, stream>>>(postbase, linW, linb, l, hc, stats);
    }

    // final BN (layer 3) -> h, then pool + MLP
    k_bnapply<<<2930, 256, 0, stream>>>(hc, stats + ((NL-1)&1)*192, bng, bnb, NL-1, h);
    k_pool<<<NG, 256, 0, stream>>>(h, batch, gpool);
    k_mlp<<<8, 256, 0, stream>>>(gpool, mlpW1, mlpb1, mlpW2, mlpb2, mlpW3, mlpb3, (float*)d_out);
}

// Round 7
// 872.860 us; speedup vs baseline: 5.5977x; 5.5977x over previous
//
#include <hip/hip_runtime.h>
#include <hip/hip_bf16.h>
#include <math.h>

#define NN 10000
#define NE 160000
#define NG 64
#define NT 5
#define NL 4
#define ADL 2.833213344056216f

// ws layout (float offsets)
#define OFF_H      0
#define OFF_HC     750000
#define OFF_P      1500000     // bf16 P during agg; reused as bf16 post partials z=0..6
#define OFF_Q      5250000     // bf16 Q
#define OFF_AGG    9000000     // bf16 agg (15M bf16 = 7.5M floats, ends 16.5M)
#define OFF_RLUT4  16500000    // 4 layers x 6000 floats
#define OFF_INVDEG 24006000
#define OFF_AMP    24016000
#define OFF_ATT    24026000
#define OFF_STATS  24036000    // 2 ping-pong buffers x 192 floats
#define OFF_GPOOL  24040000
#define OFF_INT    24118960

typedef __attribute__((ext_vector_type(2))) unsigned int uv2;

__device__ __forceinline__ float bf2f(__hip_bfloat16 v){ return __bfloat162float(v); }

__global__ void k_zero_cnt(int* cnt){
    int i = blockIdx.x*256 + threadIdx.x;
    if (i < NN) cnt[i] = 0;
}

// h0 = node_emb[x].reshape(N,150) @ pre_lin_W + b
__global__ __launch_bounds__(256) void k_h0(const int* __restrict__ x,
        const float* __restrict__ node_emb, const float* __restrict__ plW,
        const float* __restrict__ plb, float* __restrict__ h){
    __shared__ float s_emb[21*75];
    __shared__ float s_W[150*75];
    __shared__ float s_b[75];
    int tid = threadIdx.x;
    for (int i = tid; i < 21*75; i += 256) s_emb[i] = node_emb[i];
    for (int i = tid; i < 150*75; i += 256) s_W[i] = plW[i];
    if (tid < 75) s_b[tid] = plb[tid];
    __syncthreads();
    for (int out = blockIdx.x*256 + tid; out < NN*75; out += gridDim.x*256){
        int n = out / 75, f = out - n*75;
        int x0 = x[2*n], x1 = x[2*n+1];
        float acc = s_b[f];
        const float* e0 = s_emb + x0*75;
        const float* e1 = s_emb + x1*75;
        #pragma unroll 5
        for (int k = 0; k < 75; k++)
            acc += e0[k]*s_W[k*75+f] + e1[k]*s_W[(75+k)*75+f];
        h[out] = acc;
    }
}

__global__ void k_hist(const int* __restrict__ ei, int* __restrict__ cnt){
    int e = blockIdx.x*256 + threadIdx.x;
    if (e < NE) atomicAdd(&cnt[ei[NE + e]], 1);
}

// single-block prefix sum: eoff[0]=0, eoff[n+1]=inclusive prefix
__global__ void k_scan(const int* __restrict__ cnt, int* __restrict__ eoff){
    __shared__ int buf[256];
    __shared__ int carry;
    int tid = threadIdx.x;
    if (tid == 0){ carry = 0; eoff[0] = 0; }
    __syncthreads();
    for (int base = 0; base < NN; base += 256){
        int v = (base + tid < NN) ? cnt[base + tid] : 0;
        buf[tid] = v; __syncthreads();
        for (int off = 1; off < 256; off <<= 1){
            int t2 = (tid >= off) ? buf[tid - off] : 0;
            __syncthreads();
            buf[tid] += t2;
            __syncthreads();
        }
        int inc = buf[tid] + carry;
        if (base + tid < NN) eoff[base + tid + 1] = inc;
        __syncthreads();
        if (tid == 255) carry = inc;
        __syncthreads();
    }
}

__global__ void k_nodestats(const int* __restrict__ cnt, const int* __restrict__ eoff,
        float* __restrict__ invdeg, float* __restrict__ amp, float* __restrict__ att,
        int* __restrict__ cursor){
    int n = blockIdx.x*256 + threadIdx.x;
    if (n >= NN) return;
    int c = cnt[n];
    cursor[n] = eoff[n];
    float cf = (float)c;
    float dg = cf < 1.f ? 1.f : cf;
    invdeg[n] = 1.f / dg;
    float ld = logf(dg + 1.f);
    amp[n] = ld / ADL;
    att[n] = ADL / ld;
}

__global__ void k_scatter(const int* __restrict__ ei, const int* __restrict__ ea,
        int* __restrict__ cursor, int* __restrict__ esrc, int* __restrict__ ecombo){
    int e = blockIdx.x*256 + threadIdx.x;
    if (e >= NE) return;
    int src = ei[e], dst = ei[NE + e];
    int pos = atomicAdd(&cursor[dst], 1);
    esrc[pos] = src;
    ecombo[pos] = ea[2*e]*4 + ea[2*e+1];
}

// R19: Rlut depends only on weights -> hoisted out of the layer loop.
// One launch, grid (5 towers, 4 layers).
__global__ __launch_bounds__(384) void k_rlut4(
        const float* __restrict__ preW, const float* __restrict__ preb,
        const float* __restrict__ edge_emb, const float* __restrict__ encW,
        const float* __restrict__ encb, float* __restrict__ rlut_all){
    __shared__ float smem[10675];
    int tid = threadIdx.x;
    int t = blockIdx.x;
    int l = blockIdx.y;
    float* s_encW = smem;            // 50*75 = 3750
    float* s_ev   = smem + 3750;     // 16*75 = 1200
    float* s_wc   = smem + 4950;     // 75*75 = 5625
    float* s_ee   = smem + 10575;    // 100
    for (int i = tid; i < 3750; i += 384) s_encW[i] = encW[(size_t)l*3750 + i];
    for (int i = tid; i < 100; i += 384) s_ee[i] = edge_emb[i];
    const float* wcsrc = preW + (((size_t)(l*NT + t))*225 + 150)*75;
    for (int i = tid; i < 5625; i += 384) s_wc[i] = wcsrc[i];
    __syncthreads();
    for (int task = tid; task < 1200; task += 384){
        int b = task/75, m = task - 75*b;
        int a0 = b >> 2, a1 = b & 3;
        float s = encb[l*75 + m];
        for (int k = 0; k < 25; k++)
            s += s_ee[a0*25+k]*s_encW[k*75+m] + s_ee[a1*25+k]*s_encW[(25+k)*75+m];
        s_ev[task] = s;
    }
    __syncthreads();
    for (int task = tid; task < 1200; task += 384){
        int b = task/75, f = task - 75*b;
        float r = preb[((size_t)l*NT + t)*75 + f];
        const float* ev = s_ev + b*75;
        #pragma unroll 5
        for (int m = 0; m < 75; m++) r += ev[m]*s_wc[m*75 + f];
        rlut_all[(size_t)l*6000 + b*375 + t*75 + f] = r;
    }
}

// R23: k_pq = R4's proven LDS-tiled GEMM structure (2D grid, separate P/Q,
// scalar stores — R5/R6's 1D-remap + merged-PQ epilogue caused an unexplained
// 100x traffic blowup w/ scratch first-touch signature; reverted wholesale),
// now with 6x4 register blocking: 96 nodes x 64 cols per block, grid (105,12).
// R4 floor analysis: LDS b128 pipe was the limit (8 b128 per 64 FMA -> 22 us
// chip-wide); 6x4 gives 10 b128 per 96 FMA (~0.6x) amortizing VALU overhead
// too. Rows interleaved n = ty + 16*r: a wave's 4 ty-rows are consecutive ->
// h-read banks {0,12,24,4} (stride 76 floats), conflict-free. LDS 48.6 KB ->
// 3 blocks/CU.
__global__ __launch_bounds__(256, 3) void k_pq(float* __restrict__ h,
        const float* __restrict__ hc, const float* __restrict__ bng,
        const float* __restrict__ bnb,
        const float* __restrict__ preW,
        int l, __hip_bfloat16* __restrict__ P, __hip_bfloat16* __restrict__ Q,
        const float* __restrict__ stats_all){
    __shared__ float s_h[96*76];   // node-major, col 75 = 0 pad (29.2 KB)
    __shared__ float s_w[76*64];   // k-major, row 75 = 0 pad    (19.4 KB)
    int tid = threadIdx.x;
    int base_n = blockIdx.x*96;
    int base_c = blockIdx.y*64;
    int tx = tid & 15;             // col group (4 cols)
    int ty = tid >> 4;             // row base; thread rows = ty + 16*r, r=0..5

    // stage h tile (l>0: BN+ReLU from previous layer, write-back once)
    if (l == 0){
        for (int idx = tid; idx < 96*76; idx += 256){
            int i = idx/76, m = idx - 76*i;
            int n = base_n + i;
            s_h[idx] = (m < 75 && n < NN) ? h[(size_t)n*75 + m] : 0.f;
        }
    } else {
        const float* stats_rd = stats_all + ((l + 1) & 1)*192;
        int lp = l - 1;
        for (int idx = tid; idx < 96*76; idx += 256){
            int i = idx/76, m = idx - 76*i;
            int n = base_n + i;
            float v = 0.f;
            if (m < 75 && n < NN){
                float mu = stats_rd[m]*(1.0f/NN);
                float var = stats_rd[75+m]*(1.0f/NN) - mu*mu;
                float inv = rsqrtf(var + 1e-5f);
                v = (hc[(size_t)n*75 + m] - mu)*inv*bng[lp*75+m] + bnb[lp*75+m];
                v = v > 0.f ? v : 0.f;
                if (blockIdx.y == 0) h[(size_t)n*75 + m] = v;
            }
            s_h[idx] = v;
        }
    }
    // stage W tile: k-major, wave lanes cover 64 consecutive cols -> coalesced
    for (int idx = tid; idx < 76*64; idx += 256){
        int k = idx >> 6, c = idx & 63;
        int col = base_c + c;
        float v = 0.f;
        if (k < 75 && col < 750){
            int cc2 = col < 375 ? col : col - 375;
            int t = cc2/75, f = cc2 - t*75;
            int ro = col < 375 ? 0 : 75;
            v = preW[(((size_t)(l*NT + t))*225 + ro + k)*75 + f];
        }
        s_w[idx] = v;
    }
    __syncthreads();

    float acc[6][4] = {};
    const float* wrow = s_w + tx*4;
    const float* hbase = s_h + ty*76;
    for (int k4 = 0; k4 < 76; k4 += 4){
        const float4 wv0 = *(const float4*)(wrow + (k4+0)*64);
        const float4 wv1 = *(const float4*)(wrow + (k4+1)*64);
        const float4 wv2 = *(const float4*)(wrow + (k4+2)*64);
        const float4 wv3 = *(const float4*)(wrow + (k4+3)*64);
        #pragma unroll
        for (int r = 0; r < 6; r++){
            const float4 hv = *(const float4*)(hbase + r*(16*76) + k4);
            acc[r][0] += hv.x*wv0.x + hv.y*wv1.x + hv.z*wv2.x + hv.w*wv3.x;
            acc[r][1] += hv.x*wv0.y + hv.y*wv1.y + hv.z*wv2.y + hv.w*wv3.y;
            acc[r][2] += hv.x*wv0.z + hv.y*wv1.z + hv.z*wv2.z + hv.w*wv3.z;
            acc[r][3] += hv.x*wv0.w + hv.y*wv1.w + hv.z*wv2.w + hv.w*wv3.w;
        }
    }

    #pragma unroll
    for (int r = 0; r < 6; r++){
        int n = base_n + ty + 16*r;
        if (n >= NN) continue;
        #pragma unroll
        for (int cc = 0; cc < 4; cc++){
            int c = base_c + tx*4 + cc;
            if (c >= 750) continue;
            __hip_bfloat16 v = __float2bfloat16(acc[r][cc]);
            if (c < 375) P[(size_t)n*375 + c] = v;
            else         Q[(size_t)n*375 + (c - 375)] = v;
        }
    }
}

// grid (6, NN), block 64. bf16 Q gather; edge loop unrolled x8.
// R20: block (0,0) additionally zeros the BN-stats buffer for this layer
// (runs before k_lin's atomicAdds via stream ordering).
__global__ __launch_bounds__(64) void k_agg(const __hip_bfloat16* __restrict__ P,
        const __hip_bfloat16* __restrict__ Q, const float* __restrict__ Rlut,
        const int* __restrict__ eoff, const int* __restrict__ esrc,
        const int* __restrict__ ecombo, const float* __restrict__ invdeg,
        __hip_bfloat16* __restrict__ agg, float* __restrict__ stats_zero){
    int n = blockIdx.y;
    int j = blockIdx.x*64 + threadIdx.x;
    if (blockIdx.x == 0 && n == 0){
        for (int i = threadIdx.x; i < 150; i += 64) stats_zero[i] = 0.f;
    }
    if (j >= 375) return;
    int lo = eoff[n], hi = eoff[n+1];
    float p = bf2f(P[(size_t)n*375 + j]);
    float sum = 0.f, sq = 0.f, mn = 3.4e38f, mx = -3.4e38f;
    int e = lo;
    for (; e + 8 <= hi; e += 8){
        int s0 = esrc[e],   s1 = esrc[e+1], s2 = esrc[e+2], s3 = esrc[e+3];
        int s4 = esrc[e+4], s5 = esrc[e+5], s6 = esrc[e+6], s7 = esrc[e+7];
        int c0 = ecombo[e],   c1 = ecombo[e+1], c2 = ecombo[e+2], c3 = ecombo[e+3];
        int c4 = ecombo[e+4], c5 = ecombo[e+5], c6 = ecombo[e+6], c7 = ecombo[e+7];
        float q0 = bf2f(Q[(size_t)s0*375 + j]);
        float q1 = bf2f(Q[(size_t)s1*375 + j]);
        float q2 = bf2f(Q[(size_t)s2*375 + j]);
        float q3 = bf2f(Q[(size_t)s3*375 + j]);
        float q4 = bf2f(Q[(size_t)s4*375 + j]);
        float q5 = bf2f(Q[(size_t)s5*375 + j]);
        float q6 = bf2f(Q[(size_t)s6*375 + j]);
        float q7 = bf2f(Q[(size_t)s7*375 + j]);
        float r0 = Rlut[c0*375 + j], r1 = Rlut[c1*375 + j];
        float r2 = Rlut[c2*375 + j], r3 = Rlut[c3*375 + j];
        float r4 = Rlut[c4*375 + j], r5 = Rlut[c5*375 + j];
        float r6 = Rlut[c6*375 + j], r7 = Rlut[c7*375 + j];
        float m0 = p + q0 + r0, m1 = p + q1 + r1;
        float m2 = p + q2 + r2, m3 = p + q3 + r3;
        float m4 = p + q4 + r4, m5 = p + q5 + r5;
        float m6 = p + q6 + r6, m7 = p + q7 + r7;
        sum += (m0 + m1 + m2 + m3) + (m4 + m5 + m6 + m7);
        sq  += (m0*m0 + m1*m1 + m2*m2 + m3*m3) + (m4*m4 + m5*m5 + m6*m6 + m7*m7);
        mn = fminf(mn, fminf(fminf(fminf(m0,m1), fminf(m2,m3)),
                             fminf(fminf(m4,m5), fminf(m6,m7))));
        mx = fmaxf(mx, fmaxf(fmaxf(fmaxf(m0,m1), fmaxf(m2,m3)),
                             fmaxf(fmaxf(m4,m5), fmaxf(m6,m7))));
    }
    for (; e < hi; e++){
        int s = esrc[e], cm = ecombo[e];
        float m = p + bf2f(Q[(size_t)s*375 + j]) + Rlut[cm*375 + j];
        sum += m; sq += m*m;
        mn = fminf(mn, m); mx = fmaxf(mx, m);
    }
    float id = invdeg[n];
    bool has = hi > lo;
    float mean = sum*id;
    float msq  = sq*id;
    float var = msq - mean*mean; var = var > 0.f ? var : 0.f;
    float sd = sqrtf(var + 1e-5f);
    float mnv = has ? mn : 0.f;
    float mxv = has ? mx : 0.f;
    int t = j/75, f = j - 75*t;
    __hip_bfloat16* a = agg + ((size_t)n*NT + t)*300;
    a[f]      = __float2bfloat16(mean);
    a[75+f]   = __float2bfloat16(mnv);
    a[150+f]  = __float2bfloat16(mxv);
    a[225+f]  = __float2bfloat16(sd);
}

// post einsum, barrier-free; bf16 partials. grid (79, 5, 7).
// R19: 128-node tile: LDS 22.9 KB, 2765 blocks for smoother CU packing.
// R17 LDS staging retained: agg tile stride 52 ushorts, conflict-free.
#define KB2 50
__global__ __launch_bounds__(256, 6) void k_post(const float* __restrict__ h,
        const __hip_bfloat16* __restrict__ agg, const float* __restrict__ postW,
        const float* __restrict__ postb, const float* __restrict__ amp,
        const float* __restrict__ att, int l, __hip_bfloat16* __restrict__ postbase){
    __shared__ float s_w[3*KB2*16];              // 9.6 KB (z0 uses first 75*16=1200)
    __shared__ unsigned short s_a[128*52];       // 13.3 KB agg tile
    int t = blockIdx.y;
    int z = blockIdx.z;
    int nbase = blockIdx.x*128;
    int tid = threadIdx.x;
    int fg  = (tid & 3)*4;
    int sub = tid >> 2;
    const float* Wt = postW + ((size_t)(l*NT + t))*975*15;

    if (z == 0){
        for (int idx = tid; idx < 75*16; idx += 256){
            int c = idx >> 4, f = idx & 15;
            s_w[idx] = (f < 15) ? Wt[c*15 + f] : 0.f;
        }
        __syncthreads();
        float a1[2][4] = {};
        const float* hrow[2];
        #pragma unroll
        for (int j = 0; j < 2; j++){
            int n = nbase + sub + 64*j;
            hrow[j] = h + (size_t)(n < NN ? n : 0)*75;
        }
        #pragma unroll 3
        for (int k = 0; k < 75; k++){
            const float4 w1 = *(const float4*)&s_w[k*16 + fg];
            #pragma unroll
            for (int j = 0; j < 2; j++){
                float v = hrow[j][k];
                a1[j][0] += v*w1.x; a1[j][1] += v*w1.y;
                a1[j][2] += v*w1.z; a1[j][3] += v*w1.w;
            }
        }
        const float* pb = postb + (l*NT + t)*15;
        #pragma unroll
        for (int j = 0; j < 2; j++){
            int n = nbase + sub + 64*j;
            if (n >= NN) continue;
            __hip_bfloat16* dst = postbase + (size_t)n*75 + t*15;
            #pragma unroll
            for (int f = 0; f < 4; f++)
                if (fg + f < 15) dst[fg + f] = __float2bfloat16(a1[j][f] + pb[fg + f]);
        }
        return;
    }

    int kbeg = (z-1)*KB2;
    // stage weights
    for (int idx = tid; idx < 3*KB2*16; idx += 256){
        int vrow = idx / (KB2*16);
        int rem = idx - vrow*(KB2*16);
        int c = rem >> 4, f = rem & 15;
        s_w[idx] = (f < 15) ? Wt[(75 + vrow*300 + kbeg + c)*15 + f] : 0.f;
    }
    // stage agg tile: node i's 50 bf16 slice = 25 dwords, contiguous 100B runs
    {
        const unsigned short* asrc = (const unsigned short*)agg;
        for (int idx = tid; idx < 128*25; idx += 256){
            int i = idx/25, w = idx - 25*i;
            int n = nbase + i;
            unsigned int u = 0;
            if (n < NN)
                u = *(const unsigned int*)(asrc + (size_t)n*1500 + t*300 + kbeg + 2*w);
            *(unsigned int*)&s_a[i*52 + 2*w] = u;
        }
    }
    __syncthreads();

    float a1[2][4] = {}, a2[2][4] = {}, a3[2][4] = {};
    const unsigned short* ap0 = s_a + sub*52;
    #pragma unroll 2
    for (int k4 = 0; k4 < 48; k4 += 4){
        uv2 ua[2];
        #pragma unroll
        for (int j = 0; j < 2; j++)
            ua[j] = *(const uv2*)(ap0 + j*(64*52) + k4);
        #pragma unroll
        for (int kk = 0; kk < 4; kk++){
            int k = k4 + kk;
            const float4 w1 = *(const float4*)&s_w[k*16 + fg];
            const float4 w2 = *(const float4*)&s_w[(KB2 + k)*16 + fg];
            const float4 w3 = *(const float4*)&s_w[(2*KB2 + k)*16 + fg];
            #pragma unroll
            for (int j = 0; j < 2; j++){
                unsigned int bits = (kk < 2) ? ua[j].x : ua[j].y;
                float v = __uint_as_float((kk & 1) ? (bits & 0xffff0000u)
                                                   : (bits << 16));
                a1[j][0] += v*w1.x; a1[j][1] += v*w1.y;
                a1[j][2] += v*w1.z; a1[j][3] += v*w1.w;
                a2[j][0] += v*w2.x; a2[j][1] += v*w2.y;
                a2[j][2] += v*w2.z; a2[j][3] += v*w2.w;
                a3[j][0] += v*w3.x; a3[j][1] += v*w3.y;
                a3[j][2] += v*w3.z; a3[j][3] += v*w3.w;
            }
        }
    }
    // tail k = 48, 49 (one dword per row)
    {
        unsigned int ut[2];
        #pragma unroll
        for (int j = 0; j < 2; j++)
            ut[j] = *(const unsigned int*)(ap0 + j*(64*52) + 48);
        #pragma unroll
        for (int kk = 0; kk < 2; kk++){
            int k = 48 + kk;
            const float4 w1 = *(const float4*)&s_w[k*16 + fg];
            const float4 w2 = *(const float4*)&s_w[(KB2 + k)*16 + fg];
            const float4 w3 = *(const float4*)&s_w[(2*KB2 + k)*16 + fg];
            #pragma unroll
            for (int j = 0; j < 2; j++){
                float v = __uint_as_float((kk & 1) ? (ut[j] & 0xffff0000u)
                                                   : (ut[j] << 16));
                a1[j][0] += v*w1.x; a1[j][1] += v*w1.y;
                a1[j][2] += v*w1.z; a1[j][3] += v*w1.w;
                a2[j][0] += v*w2.x; a2[j][1] += v*w2.y;
                a2[j][2] += v*w2.z; a2[j][3] += v*w2.w;
                a3[j][0] += v*w3.x; a3[j][1] += v*w3.y;
                a3[j][2] += v*w3.z; a3[j][3] += v*w3.w;
            }
        }
    }
    __hip_bfloat16* postv = postbase + (size_t)z*750000;
    #pragma unroll
    for (int j = 0; j < 2; j++){
        int n = nbase + sub + 64*j;
        if (n >= NN) continue;
        float am = amp[n], at = att[n];
        __hip_bfloat16* dst = postv + (size_t)n*75 + t*15;
        #pragma unroll
        for (int f = 0; f < 4; f++)
            if (fg + f < 15)
                dst[fg + f] = __float2bfloat16(a1[j][f] + am*a2[j][f] + at*a3[j][f]);
    }
}

// hc = (Σz postz) @ lin_W[l] + lin_b[l]; fused BN-stat reduction into buffer l&1.
__global__ __launch_bounds__(256) void k_lin(const __hip_bfloat16* __restrict__ postbase,
        const float* __restrict__ linW, const float* __restrict__ linb,
        int l, float* __restrict__ hc, float* __restrict__ stats_all){
    __shared__ float p_l[32*75];
    __shared__ float w_l[75*75];
    __shared__ float hc_l[32*75];
    int tid = threadIdx.x;
    int base = blockIdx.x*32;
    for (int i = tid; i < 75*75; i += 256) w_l[i] = linW[(size_t)l*5625 + i];
    for (int i = tid; i < 32*75; i += 256){
        int n = base + i/75;
        size_t idx = (size_t)base*75 + i;
        float v = 0.f;
        if (n < NN){
            #pragma unroll
            for (int z = 0; z < 7; z++) v += bf2f(postbase[idx + (size_t)z*750000]);
        }
        p_l[i] = v;
    }
    __syncthreads();
    for (int task = tid; task < 2400; task += 256){
        int i = task/75, o = task - 75*i;
        float s = linb[l*75 + o];
        const float* pl = p_l + i*75;
        #pragma unroll 5
        for (int j = 0; j < 75; j++) s += pl[j]*w_l[j*75 + o];
        hc_l[task] = s;
        if (base + i < NN) hc[(size_t)(base+i)*75 + o] = s;
    }
    __syncthreads();
    if (tid < 75){
        float* stats_wr = stats_all + (l & 1)*192;
        int nv = NN - base; if (nv > 32) nv = 32;
        float s1 = 0.f, s2 = 0.f;
        for (int i = 0; i < nv; i++){
            float v = hc_l[i*75 + tid];
            s1 += v; s2 += v*v;
        }
        atomicAdd(&stats_wr[tid], s1);
        atomicAdd(&stats_wr[75+tid], s2);
    }
}

// final BN apply (only after last layer; earlier layers fused into k_pq)
__global__ void k_bnapply(const float* __restrict__ hc, const float* __restrict__ stats,
        const float* __restrict__ bng, const float* __restrict__ bnb, int l,
        float* __restrict__ h){
    int idx = blockIdx.x*256 + threadIdx.x;
    if (idx >= NN*75) return;
    int col = idx % 75;
    float mu = stats[col]*(1.0f/NN);
    float var = stats[75+col]*(1.0f/NN) - mu*mu;
    float inv = rsqrtf(var + 1e-5f);
    float v = (hc[idx] - mu)*inv*bng[l*75+col] + bnb[l*75+col];
    h[idx] = v > 0.f ? v : 0.f;
}

__global__ __launch_bounds__(256) void k_pool(const float* __restrict__ h,
        const int* __restrict__ batch, float* __restrict__ gpool){
    int g = blockIdx.x, tid = threadIdx.x;
    int lo = 0, hi = NN;
    while (lo < hi){ int mid = (lo+hi)>>1; if (batch[mid] < g) lo = mid+1; else hi = mid; }
    int start = lo;
    lo = start; hi = NN;
    while (lo < hi){ int mid = (lo+hi)>>1; if (batch[mid] < g+1) lo = mid+1; else hi = mid; }
    int end = lo;
    __shared__ float red[225];
    if (tid < 225){
        int col = tid % 75, rep = tid / 75;
        float acc = 0.f;
        for (int i = start + rep; i < end; i += 3) acc += h[(size_t)i*75 + col];
        red[tid] = acc;
    }
    __syncthreads();
    if (tid < 75) gpool[g*75 + tid] = red[tid] + red[75+tid] + red[150+tid];
}

// 8 blocks x 8 graphs; weights in LDS, phase-parallel
__global__ __launch_bounds__(256) void k_mlp(const float* __restrict__ gpool,
        const float* __restrict__ W1, const float* __restrict__ b1,
        const float* __restrict__ W2, const float* __restrict__ b2,
        const float* __restrict__ W3, const float* __restrict__ b3,
        float* __restrict__ out){
    __shared__ float w1[75*50];
    __shared__ float w2[50*25];
    __shared__ float gp[8*75];
    __shared__ float t1[8*50];
    __shared__ float t2[8*25];
    int tid = threadIdx.x;
    int gbase = blockIdx.x*8;
    for (int i = tid; i < 75*50; i += 256) w1[i] = W1[i];
    for (int i = tid; i < 50*25; i += 256) w2[i] = W2[i];
    for (int i = tid; i < 8*75; i += 256) gp[i] = gpool[gbase*75 + i];
    __syncthreads();
    for (int task = tid; task < 8*50; task += 256){
        int g = task/50, j = task - 50*g;
        float s = b1[j];
        const float* gv = gp + g*75;
        #pragma unroll 5
        for (int k = 0; k < 75; k++) s += gv[k]*w1[k*50+j];
        t1[task] = s > 0.f ? s : 0.f;
    }
    __syncthreads();
    for (int task = tid; task < 8*25; task += 256){
        int g = task/25, j = task - 25*g;
        float s = b2[j];
        const float* tv = t1 + g*50;
        #pragma unroll 5
        for (int k = 0; k < 50; k++) s += tv[k]*w2[k*25+j];
        t2[task] = s > 0.f ? s : 0.f;
    }
    __syncthreads();
    if (tid < 8){
        float s = b3[0];
        const float* tv = t2 + tid*25;
        #pragma unroll
        for (int k = 0; k < 25; k++) s += tv[k]*W3[k];
        out[gbase + tid] = s;
    }
}

extern "C" void kernel_launch(void* const* d_in, const int* in_sizes, int n_in,
                              void* d_out, int out_size, void* d_ws, size_t ws_size,
                              hipStream_t stream){
    const int* x          = (const int*)d_in[0];
    const int* edge_index = (const int*)d_in[1];
    const int* edge_attr  = (const int*)d_in[2];
    const int* batch      = (const int*)d_in[3];
    const float* node_emb = (const float*)d_in[4];
    const float* edge_emb = (const float*)d_in[5];
    const float* pre_lin_W= (const float*)d_in[6];
    const float* pre_lin_b= (const float*)d_in[7];
    const float* encW     = (const float*)d_in[8];
    const float* encb     = (const float*)d_in[9];
    const float* preW     = (const float*)d_in[10];
    const float* preb     = (const float*)d_in[11];
    const float* postW    = (const float*)d_in[12];
    const float* postb    = (const float*)d_in[13];
    const float* linW     = (const float*)d_in[14];
    const float* linb     = (const float*)d_in[15];
    const float* bng      = (const float*)d_in[16];
    const float* bnb      = (const float*)d_in[17];
    const float* mlpW1    = (const float*)d_in[18];
    const float* mlpb1    = (const float*)d_in[19];
    const float* mlpW2    = (const float*)d_in[20];
    const float* mlpb2    = (const float*)d_in[21];
    const float* mlpW3    = (const float*)d_in[22];
    const float* mlpb3    = (const float*)d_in[23];

    float* ws = (float*)d_ws;
    float* h      = ws + OFF_H;
    float* hc     = ws + OFF_HC;
    __hip_bfloat16* P = (__hip_bfloat16*)(ws + OFF_P);
    __hip_bfloat16* Q = (__hip_bfloat16*)(ws + OFF_Q);
    __hip_bfloat16* agg = (__hip_bfloat16*)(ws + OFF_AGG);
    float* rlut4  = ws + OFF_RLUT4;
    float* invdeg = ws + OFF_INVDEG;
    float* amp    = ws + OFF_AMP;
    float* att    = ws + OFF_ATT;
    float* stats  = ws + OFF_STATS;   // 2 x 192 ping-pong
    float* gpool  = ws + OFF_GPOOL;
    __hip_bfloat16* postbase = (__hip_bfloat16*)(ws + OFF_P);  // bf16 partials z=0..6
    int* iw     = (int*)(ws + OFF_INT);
    int* cnt    = iw;
    int* eoff   = cnt + NN;        // NN+1
    int* cursor = eoff + NN + 2;
    int* esrc   = cursor + NN;
    int* ecombo = esrc + NE;

    k_zero_cnt<<<40, 256, 0, stream>>>(cnt);
    k_rlut4<<<dim3(5, 4), 384, 0, stream>>>(preW, preb, edge_emb, encW, encb, rlut4);
    k_h0<<<640, 256, 0, stream>>>(x, node_emb, pre_lin_W, pre_lin_b, h);
    k_hist<<<625, 256, 0, stream>>>(edge_index, cnt);
    k_scan<<<1, 256, 0, stream>>>(cnt, eoff);
    k_nodestats<<<40, 256, 0, stream>>>(cnt, eoff, invdeg, amp, att, cursor);
    k_scatter<<<625, 256, 0, stream>>>(edge_index, edge_attr, cursor, esrc, ecombo);

    for (int l = 0; l < NL; l++){
        k_pq<<<dim3(105, 12), 256, 0, stream>>>(h, hc, bng, bnb, preW, l, P, Q, stats);
        k_agg<<<dim3(6, NN), 64, 0, stream>>>(P, Q, rlut4 + (size_t)l*6000,
                                              eoff, esrc, ecombo, invdeg, agg,
                                              stats + (l & 1)*192);
        k_post<<<dim3(79, 5, 7), 256, 0, stream>>>(h, agg, postW, postb, amp, att, l, postbase);
        k_lin<<<313, 256, 0, stream>>>(postbase, linW, linb, l, hc, stats);
    }

    // final BN (layer 3) -> h, then pool + MLP
    k_bnapply<<<2930, 256, 0, stream>>>(hc, stats + ((NL-1)&1)*192, bng, bnb, NL-1, h);
    k_pool<<<NG, 256, 0, stream>>>(h, batch, gpool);
    k_mlp<<<8, 256, 0, stream>>>(gpool, mlpW1, mlpb1, mlpW2, mlpb2, mlpW3, mlpb3, (float*)d_out);
}

// Round 8
// 858.560 us; speedup vs baseline: 5.6910x; 1.0167x over previous
//
#include <hip/hip_runtime.h>
#include <hip/hip_bf16.h>
#include <math.h>

#define NN 10000
#define NE 160000
#define NG 64
#define NT 5
#define NL 4
#define ADL 2.833213344056216f

// ws layout (float offsets)
#define OFF_H      0
#define OFF_HC     750000
#define OFF_P      1500000     // bf16 P during agg; reused as bf16 post partials z=0..6
#define OFF_Q      5250000     // bf16 Q
#define OFF_AGG    9000000     // bf16 agg (15M bf16 = 7.5M floats, ends 16.5M)
#define OFF_RLUT4  16500000    // 4 layers x 6000 floats
#define OFF_INVDEG 24006000
#define OFF_AMP    24016000
#define OFF_ATT    24026000
#define OFF_STATS  24036000    // 2 ping-pong buffers x 192 floats
#define OFF_GPOOL  24040000
#define OFF_INT    24118960

typedef __attribute__((ext_vector_type(2))) unsigned int uv2;

__device__ __forceinline__ float bf2f(__hip_bfloat16 v){ return __bfloat162float(v); }

__global__ void k_zero_cnt(int* cnt){
    int i = blockIdx.x*256 + threadIdx.x;
    if (i < NN) cnt[i] = 0;
}

// h0 = node_emb[x].reshape(N,150) @ pre_lin_W + b
__global__ __launch_bounds__(256) void k_h0(const int* __restrict__ x,
        const float* __restrict__ node_emb, const float* __restrict__ plW,
        const float* __restrict__ plb, float* __restrict__ h){
    __shared__ float s_emb[21*75];
    __shared__ float s_W[150*75];
    __shared__ float s_b[75];
    int tid = threadIdx.x;
    for (int i = tid; i < 21*75; i += 256) s_emb[i] = node_emb[i];
    for (int i = tid; i < 150*75; i += 256) s_W[i] = plW[i];
    if (tid < 75) s_b[tid] = plb[tid];
    __syncthreads();
    for (int out = blockIdx.x*256 + tid; out < NN*75; out += gridDim.x*256){
        int n = out / 75, f = out - n*75;
        int x0 = x[2*n], x1 = x[2*n+1];
        float acc = s_b[f];
        const float* e0 = s_emb + x0*75;
        const float* e1 = s_emb + x1*75;
        #pragma unroll 5
        for (int k = 0; k < 75; k++)
            acc += e0[k]*s_W[k*75+f] + e1[k]*s_W[(75+k)*75+f];
        h[out] = acc;
    }
}

__global__ void k_hist(const int* __restrict__ ei, int* __restrict__ cnt){
    int e = blockIdx.x*256 + threadIdx.x;
    if (e < NE) atomicAdd(&cnt[ei[NE + e]], 1);
}

// single-block prefix sum: eoff[0]=0, eoff[n+1]=inclusive prefix
__global__ void k_scan(const int* __restrict__ cnt, int* __restrict__ eoff){
    __shared__ int buf[256];
    __shared__ int carry;
    int tid = threadIdx.x;
    if (tid == 0){ carry = 0; eoff[0] = 0; }
    __syncthreads();
    for (int base = 0; base < NN; base += 256){
        int v = (base + tid < NN) ? cnt[base + tid] : 0;
        buf[tid] = v; __syncthreads();
        for (int off = 1; off < 256; off <<= 1){
            int t2 = (tid >= off) ? buf[tid - off] : 0;
            __syncthreads();
            buf[tid] += t2;
            __syncthreads();
        }
        int inc = buf[tid] + carry;
        if (base + tid < NN) eoff[base + tid + 1] = inc;
        __syncthreads();
        if (tid == 255) carry = inc;
        __syncthreads();
    }
}

__global__ void k_nodestats(const int* __restrict__ cnt, const int* __restrict__ eoff,
        float* __restrict__ invdeg, float* __restrict__ amp, float* __restrict__ att,
        int* __restrict__ cursor){
    int n = blockIdx.x*256 + threadIdx.x;
    if (n >= NN) return;
    int c = cnt[n];
    cursor[n] = eoff[n];
    float cf = (float)c;
    float dg = cf < 1.f ? 1.f : cf;
    invdeg[n] = 1.f / dg;
    float ld = logf(dg + 1.f);
    amp[n] = ld / ADL;
    att[n] = ADL / ld;
}

__global__ void k_scatter(const int* __restrict__ ei, const int* __restrict__ ea,
        int* __restrict__ cursor, int* __restrict__ esrc, int* __restrict__ ecombo){
    int e = blockIdx.x*256 + threadIdx.x;
    if (e >= NE) return;
    int src = ei[e], dst = ei[NE + e];
    int pos = atomicAdd(&cursor[dst], 1);
    esrc[pos] = src;
    ecombo[pos] = ea[2*e]*4 + ea[2*e+1];
}

// R19: Rlut depends only on weights -> hoisted out of the layer loop.
// One launch, grid (5 towers, 4 layers).
__global__ __launch_bounds__(384) void k_rlut4(
        const float* __restrict__ preW, const float* __restrict__ preb,
        const float* __restrict__ edge_emb, const float* __restrict__ encW,
        const float* __restrict__ encb, float* __restrict__ rlut_all){
    __shared__ float smem[10675];
    int tid = threadIdx.x;
    int t = blockIdx.x;
    int l = blockIdx.y;
    float* s_encW = smem;            // 50*75 = 3750
    float* s_ev   = smem + 3750;     // 16*75 = 1200
    float* s_wc   = smem + 4950;     // 75*75 = 5625
    float* s_ee   = smem + 10575;    // 100
    for (int i = tid; i < 3750; i += 384) s_encW[i] = encW[(size_t)l*3750 + i];
    for (int i = tid; i < 100; i += 384) s_ee[i] = edge_emb[i];
    const float* wcsrc = preW + (((size_t)(l*NT + t))*225 + 150)*75;
    for (int i = tid; i < 5625; i += 384) s_wc[i] = wcsrc[i];
    __syncthreads();
    for (int task = tid; task < 1200; task += 384){
        int b = task/75, m = task - 75*b;
        int a0 = b >> 2, a1 = b & 3;
        float s = encb[l*75 + m];
        for (int k = 0; k < 25; k++)
            s += s_ee[a0*25+k]*s_encW[k*75+m] + s_ee[a1*25+k]*s_encW[(25+k)*75+m];
        s_ev[task] = s;
    }
    __syncthreads();
    for (int task = tid; task < 1200; task += 384){
        int b = task/75, f = task - 75*b;
        float r = preb[((size_t)l*NT + t)*75 + f];
        const float* ev = s_ev + b*75;
        #pragma unroll 5
        for (int m = 0; m < 75; m++) r += ev[m]*s_wc[m*75 + f];
        rlut_all[(size_t)l*6000 + b*375 + t*75 + f] = r;
    }
}

// R24 = exact R4 k_pq (best measured: 50.5 us, 33% occ, FETCH 17MB).
// LDS-tiled GEMM C[10000 x 750] = h[10000 x 75] @ Wc[75 x 750].
// Block = 64 nodes x 64 cols, K padded to 76. 256 threads, 4x4 tile each.
// R7's 96x64 / 6x4 variant regressed (LDS 48.6KB -> 3 blk/CU -> occ 24%,
// 56.4us): k_pq responds to occupancy, not LDS-issue count. Do not grow tile.
// l>0: staging applies previous layer's BN+ReLU; only blockIdx.y==0 writes h.
__global__ __launch_bounds__(256, 4) void k_pq(float* __restrict__ h,
        const float* __restrict__ hc, const float* __restrict__ bng,
        const float* __restrict__ bnb,
        const float* __restrict__ preW,
        int l, __hip_bfloat16* __restrict__ P, __hip_bfloat16* __restrict__ Q,
        const float* __restrict__ stats_all){
    __shared__ float s_h[64*76];   // node-major, col 75 = 0 pad
    __shared__ float s_w[76*64];   // k-major, row 75 = 0 pad
    int tid = threadIdx.x;
    int base_n = blockIdx.x*64;
    int base_c = blockIdx.y*64;
    int tx = tid & 15;             // col group (4 cols)
    int ty = tid >> 4;             // node group (4 nodes)

    // stage h tile (l>0: BN+ReLU from previous layer, write-back once)
    if (l == 0){
        for (int idx = tid; idx < 64*76; idx += 256){
            int i = idx/76, m = idx - 76*i;
            int n = base_n + i;
            s_h[idx] = (m < 75 && n < NN) ? h[(size_t)n*75 + m] : 0.f;
        }
    } else {
        const float* stats_rd = stats_all + ((l + 1) & 1)*192;
        int lp = l - 1;
        for (int idx = tid; idx < 64*76; idx += 256){
            int i = idx/76, m = idx - 76*i;
            int n = base_n + i;
            float v = 0.f;
            if (m < 75 && n < NN){
                float mu = stats_rd[m]*(1.0f/NN);
                float var = stats_rd[75+m]*(1.0f/NN) - mu*mu;
                float inv = rsqrtf(var + 1e-5f);
                v = (hc[(size_t)n*75 + m] - mu)*inv*bng[lp*75+m] + bnb[lp*75+m];
                v = v > 0.f ? v : 0.f;
                if (blockIdx.y == 0) h[(size_t)n*75 + m] = v;
            }
            s_h[idx] = v;
        }
    }
    // stage W tile: k-major, wave lanes cover 64 consecutive cols -> coalesced
    for (int idx = tid; idx < 76*64; idx += 256){
        int k = idx >> 6, c = idx & 63;
        int col = base_c + c;
        float v = 0.f;
        if (k < 75 && col < 750){
            int cc2 = col < 375 ? col : col - 375;
            int t = cc2/75, f = cc2 - t*75;
            int ro = col < 375 ? 0 : 75;
            v = preW[(((size_t)(l*NT + t))*225 + ro + k)*75 + f];
        }
        s_w[idx] = v;
    }
    __syncthreads();

    float acc[4][4] = {};
    const float* hrow = s_h + (ty*4)*76;
    const float* wrow = s_w + tx*4;
    for (int k4 = 0; k4 < 76; k4 += 4){
        float4 hv[4], wv[4];
        #pragma unroll
        for (int r = 0; r < 4; r++)
            hv[r] = *(const float4*)(hrow + r*76 + k4);
        #pragma unroll
        for (int kk = 0; kk < 4; kk++)
            wv[kk] = *(const float4*)(wrow + (k4+kk)*64);
        #pragma unroll
        for (int r = 0; r < 4; r++){
            float h0 = hv[r].x, h1 = hv[r].y, h2 = hv[r].z, h3 = hv[r].w;
            acc[r][0] += h0*wv[0].x + h1*wv[1].x + h2*wv[2].x + h3*wv[3].x;
            acc[r][1] += h0*wv[0].y + h1*wv[1].y + h2*wv[2].y + h3*wv[3].y;
            acc[r][2] += h0*wv[0].z + h1*wv[1].z + h2*wv[2].z + h3*wv[3].z;
            acc[r][3] += h0*wv[0].w + h1*wv[1].w + h2*wv[2].w + h3*wv[3].w;
        }
    }

    #pragma unroll
    for (int r = 0; r < 4; r++){
        int n = base_n + ty*4 + r;
        if (n >= NN) continue;
        #pragma unroll
        for (int cc = 0; cc < 4; cc++){
            int c = base_c + tx*4 + cc;
            if (c >= 750) continue;
            __hip_bfloat16 v = __float2bfloat16(acc[r][cc]);
            if (c < 375) P[(size_t)n*375 + c] = v;
            else         Q[(size_t)n*375 + (c - 375)] = v;
        }
    }
}

// grid (6, NN), block 64. bf16 Q gather; edge loop unrolled x8.
// R20: block (0,0) additionally zeros the BN-stats buffer for this layer
// (runs before k_lin's atomicAdds via stream ordering).
__global__ __launch_bounds__(64) void k_agg(const __hip_bfloat16* __restrict__ P,
        const __hip_bfloat16* __restrict__ Q, const float* __restrict__ Rlut,
        const int* __restrict__ eoff, const int* __restrict__ esrc,
        const int* __restrict__ ecombo, const float* __restrict__ invdeg,
        __hip_bfloat16* __restrict__ agg, float* __restrict__ stats_zero){
    int n = blockIdx.y;
    int j = blockIdx.x*64 + threadIdx.x;
    if (blockIdx.x == 0 && n == 0){
        for (int i = threadIdx.x; i < 150; i += 64) stats_zero[i] = 0.f;
    }
    if (j >= 375) return;
    int lo = eoff[n], hi = eoff[n+1];
    float p = bf2f(P[(size_t)n*375 + j]);
    float sum = 0.f, sq = 0.f, mn = 3.4e38f, mx = -3.4e38f;
    int e = lo;
    for (; e + 8 <= hi; e += 8){
        int s0 = esrc[e],   s1 = esrc[e+1], s2 = esrc[e+2], s3 = esrc[e+3];
        int s4 = esrc[e+4], s5 = esrc[e+5], s6 = esrc[e+6], s7 = esrc[e+7];
        int c0 = ecombo[e],   c1 = ecombo[e+1], c2 = ecombo[e+2], c3 = ecombo[e+3];
        int c4 = ecombo[e+4], c5 = ecombo[e+5], c6 = ecombo[e+6], c7 = ecombo[e+7];
        float q0 = bf2f(Q[(size_t)s0*375 + j]);
        float q1 = bf2f(Q[(size_t)s1*375 + j]);
        float q2 = bf2f(Q[(size_t)s2*375 + j]);
        float q3 = bf2f(Q[(size_t)s3*375 + j]);
        float q4 = bf2f(Q[(size_t)s4*375 + j]);
        float q5 = bf2f(Q[(size_t)s5*375 + j]);
        float q6 = bf2f(Q[(size_t)s6*375 + j]);
        float q7 = bf2f(Q[(size_t)s7*375 + j]);
        float r0 = Rlut[c0*375 + j], r1 = Rlut[c1*375 + j];
        float r2 = Rlut[c2*375 + j], r3 = Rlut[c3*375 + j];
        float r4 = Rlut[c4*375 + j], r5 = Rlut[c5*375 + j];
        float r6 = Rlut[c6*375 + j], r7 = Rlut[c7*375 + j];
        float m0 = p + q0 + r0, m1 = p + q1 + r1;
        float m2 = p + q2 + r2, m3 = p + q3 + r3;
        float m4 = p + q4 + r4, m5 = p + q5 + r5;
        float m6 = p + q6 + r6, m7 = p + q7 + r7;
        sum += (m0 + m1 + m2 + m3) + (m4 + m5 + m6 + m7);
        sq  += (m0*m0 + m1*m1 + m2*m2 + m3*m3) + (m4*m4 + m5*m5 + m6*m6 + m7*m7);
        mn = fminf(mn, fminf(fminf(fminf(m0,m1), fminf(m2,m3)),
                             fminf(fminf(m4,m5), fminf(m6,m7))));
        mx = fmaxf(mx, fmaxf(fmaxf(fmaxf(m0,m1), fmaxf(m2,m3)),
                             fmaxf(fmaxf(m4,m5), fmaxf(m6,m7))));
    }
    for (; e < hi; e++){
        int s = esrc[e], cm = ecombo[e];
        float m = p + bf2f(Q[(size_t)s*375 + j]) + Rlut[cm*375 + j];
        sum += m; sq += m*m;
        mn = fminf(mn, m); mx = fmaxf(mx, m);
    }
    float id = invdeg[n];
    bool has = hi > lo;
    float mean = sum*id;
    float msq  = sq*id;
    float var = msq - mean*mean; var = var > 0.f ? var : 0.f;
    float sd = sqrtf(var + 1e-5f);
    float mnv = has ? mn : 0.f;
    float mxv = has ? mx : 0.f;
    int t = j/75, f = j - 75*t;
    __hip_bfloat16* a = agg + ((size_t)n*NT + t)*300;
    a[f]      = __float2bfloat16(mean);
    a[75+f]   = __float2bfloat16(mnv);
    a[150+f]  = __float2bfloat16(mxv);
    a[225+f]  = __float2bfloat16(sd);
}

// post einsum, barrier-free; bf16 partials. grid (79, 5, 7).
// R19: 128-node tile: LDS 22.9 KB, 2765 blocks for smoother CU packing.
// R17 LDS staging retained: agg tile stride 52 ushorts, conflict-free.
#define KB2 50
__global__ __launch_bounds__(256, 6) void k_post(const float* __restrict__ h,
        const __hip_bfloat16* __restrict__ agg, const float* __restrict__ postW,
        const float* __restrict__ postb, const float* __restrict__ amp,
        const float* __restrict__ att, int l, __hip_bfloat16* __restrict__ postbase){
    __shared__ float s_w[3*KB2*16];              // 9.6 KB (z0 uses first 75*16=1200)
    __shared__ unsigned short s_a[128*52];       // 13.3 KB agg tile
    int t = blockIdx.y;
    int z = blockIdx.z;
    int nbase = blockIdx.x*128;
    int tid = threadIdx.x;
    int fg  = (tid & 3)*4;
    int sub = tid >> 2;
    const float* Wt = postW + ((size_t)(l*NT + t))*975*15;

    if (z == 0){
        for (int idx = tid; idx < 75*16; idx += 256){
            int c = idx >> 4, f = idx & 15;
            s_w[idx] = (f < 15) ? Wt[c*15 + f] : 0.f;
        }
        __syncthreads();
        float a1[2][4] = {};
        const float* hrow[2];
        #pragma unroll
        for (int j = 0; j < 2; j++){
            int n = nbase + sub + 64*j;
            hrow[j] = h + (size_t)(n < NN ? n : 0)*75;
        }
        #pragma unroll 3
        for (int k = 0; k < 75; k++){
            const float4 w1 = *(const float4*)&s_w[k*16 + fg];
            #pragma unroll
            for (int j = 0; j < 2; j++){
                float v = hrow[j][k];
                a1[j][0] += v*w1.x; a1[j][1] += v*w1.y;
                a1[j][2] += v*w1.z; a1[j][3] += v*w1.w;
            }
        }
        const float* pb = postb + (l*NT + t)*15;
        #pragma unroll
        for (int j = 0; j < 2; j++){
            int n = nbase + sub + 64*j;
            if (n >= NN) continue;
            __hip_bfloat16* dst = postbase + (size_t)n*75 + t*15;
            #pragma unroll
            for (int f = 0; f < 4; f++)
                if (fg + f < 15) dst[fg + f] = __float2bfloat16(a1[j][f] + pb[fg + f]);
        }
        return;
    }

    int kbeg = (z-1)*KB2;
    // stage weights
    for (int idx = tid; idx < 3*KB2*16; idx += 256){
        int vrow = idx / (KB2*16);
        int rem = idx - vrow*(KB2*16);
        int c = rem >> 4, f = rem & 15;
        s_w[idx] = (f < 15) ? Wt[(75 + vrow*300 + kbeg + c)*15 + f] : 0.f;
    }
    // stage agg tile: node i's 50 bf16 slice = 25 dwords, contiguous 100B runs
    {
        const unsigned short* asrc = (const unsigned short*)agg;
        for (int idx = tid; idx < 128*25; idx += 256){
            int i = idx/25, w = idx - 25*i;
            int n = nbase + i;
            unsigned int u = 0;
            if (n < NN)
                u = *(const unsigned int*)(asrc + (size_t)n*1500 + t*300 + kbeg + 2*w);
            *(unsigned int*)&s_a[i*52 + 2*w] = u;
        }
    }
    __syncthreads();

    float a1[2][4] = {}, a2[2][4] = {}, a3[2][4] = {};
    const unsigned short* ap0 = s_a + sub*52;
    #pragma unroll 2
    for (int k4 = 0; k4 < 48; k4 += 4){
        uv2 ua[2];
        #pragma unroll
        for (int j = 0; j < 2; j++)
            ua[j] = *(const uv2*)(ap0 + j*(64*52) + k4);
        #pragma unroll
        for (int kk = 0; kk < 4; kk++){
            int k = k4 + kk;
            const float4 w1 = *(const float4*)&s_w[k*16 + fg];
            const float4 w2 = *(const float4*)&s_w[(KB2 + k)*16 + fg];
            const float4 w3 = *(const float4*)&s_w[(2*KB2 + k)*16 + fg];
            #pragma unroll
            for (int j = 0; j < 2; j++){
                unsigned int bits = (kk < 2) ? ua[j].x : ua[j].y;
                float v = __uint_as_float((kk & 1) ? (bits & 0xffff0000u)
                                                   : (bits << 16));
                a1[j][0] += v*w1.x; a1[j][1] += v*w1.y;
                a1[j][2] += v*w1.z; a1[j][3] += v*w1.w;
                a2[j][0] += v*w2.x; a2[j][1] += v*w2.y;
                a2[j][2] += v*w2.z; a2[j][3] += v*w2.w;
                a3[j][0] += v*w3.x; a3[j][1] += v*w3.y;
                a3[j][2] += v*w3.z; a3[j][3] += v*w3.w;
            }
        }
    }
    // tail k = 48, 49 (one dword per row)
    {
        unsigned int ut[2];
        #pragma unroll
        for (int j = 0; j < 2; j++)
            ut[j] = *(const unsigned int*)(ap0 + j*(64*52) + 48);
        #pragma unroll
        for (int kk = 0; kk < 2; kk++){
            int k = 48 + kk;
            const float4 w1 = *(const float4*)&s_w[k*16 + fg];
            const float4 w2 = *(const float4*)&s_w[(KB2 + k)*16 + fg];
            const float4 w3 = *(const float4*)&s_w[(2*KB2 + k)*16 + fg];
            #pragma unroll
            for (int j = 0; j < 2; j++){
                float v = __uint_as_float((kk & 1) ? (ut[j] & 0xffff0000u)
                                                   : (ut[j] << 16));
                a1[j][0] += v*w1.x; a1[j][1] += v*w1.y;
                a1[j][2] += v*w1.z; a1[j][3] += v*w1.w;
                a2[j][0] += v*w2.x; a2[j][1] += v*w2.y;
                a2[j][2] += v*w2.z; a2[j][3] += v*w2.w;
                a3[j][0] += v*w3.x; a3[j][1] += v*w3.y;
                a3[j][2] += v*w3.z; a3[j][3] += v*w3.w;
            }
        }
    }
    __hip_bfloat16* postv = postbase + (size_t)z*750000;
    #pragma unroll
    for (int j = 0; j < 2; j++){
        int n = nbase + sub + 64*j;
        if (n >= NN) continue;
        float am = amp[n], at = att[n];
        __hip_bfloat16* dst = postv + (size_t)n*75 + t*15;
        #pragma unroll
        for (int f = 0; f < 4; f++)
            if (fg + f < 15)
                dst[fg + f] = __float2bfloat16(a1[j][f] + am*a2[j][f] + at*a3[j][f]);
    }
}

// hc = (Σz postz) @ lin_W[l] + lin_b[l]; fused BN-stat reduction into buffer l&1.
// R24: 16 nodes/block x 625 blocks (was 32 x 313 = 1.22 blocks/CU, occupancy-
// starved: 41.7 KB LDS w/ 9.4 serial 75-FMA dots/thread and nothing to hide
// latency). Now LDS 32.1 KB (4 blocks/CU), 2.4 blocks/CU avg, serial work
// halved. Weight re-read doubles (7 -> 14 MB, L2-served, absorbed).
__global__ __launch_bounds__(256) void k_lin(const __hip_bfloat16* __restrict__ postbase,
        const float* __restrict__ linW, const float* __restrict__ linb,
        int l, float* __restrict__ hc, float* __restrict__ stats_all){
    __shared__ float p_l[16*75];
    __shared__ float w_l[75*75];
    __shared__ float hc_l[16*75];
    int tid = threadIdx.x;
    int base = blockIdx.x*16;
    for (int i = tid; i < 75*75; i += 256) w_l[i] = linW[(size_t)l*5625 + i];
    for (int i = tid; i < 16*75; i += 256){
        int n = base + i/75;
        size_t idx = (size_t)base*75 + i;
        float v = 0.f;
        if (n < NN){
            #pragma unroll
            for (int z = 0; z < 7; z++) v += bf2f(postbase[idx + (size_t)z*750000]);
        }
        p_l[i] = v;
    }
    __syncthreads();
    for (int task = tid; task < 1200; task += 256){
        int i = task/75, o = task - 75*i;
        float s = linb[l*75 + o];
        const float* pl = p_l + i*75;
        #pragma unroll 5
        for (int j = 0; j < 75; j++) s += pl[j]*w_l[j*75 + o];
        hc_l[task] = s;
        if (base + i < NN) hc[(size_t)(base+i)*75 + o] = s;
    }
    __syncthreads();
    if (tid < 75){
        float* stats_wr = stats_all + (l & 1)*192;
        int nv = NN - base; if (nv > 16) nv = 16;
        float s1 = 0.f, s2 = 0.f;
        for (int i = 0; i < nv; i++){
            float v = hc_l[i*75 + tid];
            s1 += v; s2 += v*v;
        }
        atomicAdd(&stats_wr[tid], s1);
        atomicAdd(&stats_wr[75+tid], s2);
    }
}

// final BN apply (only after last layer; earlier layers fused into k_pq)
__global__ void k_bnapply(const float* __restrict__ hc, const float* __restrict__ stats,
        const float* __restrict__ bng, const float* __restrict__ bnb, int l,
        float* __restrict__ h){
    int idx = blockIdx.x*256 + threadIdx.x;
    if (idx >= NN*75) return;
    int col = idx % 75;
    float mu = stats[col]*(1.0f/NN);
    float var = stats[75+col]*(1.0f/NN) - mu*mu;
    float inv = rsqrtf(var + 1e-5f);
    float v = (hc[idx] - mu)*inv*bng[l*75+col] + bnb[l*75+col];
    h[idx] = v > 0.f ? v : 0.f;
}

__global__ __launch_bounds__(256) void k_pool(const float* __restrict__ h,
        const int* __restrict__ batch, float* __restrict__ gpool){
    int g = blockIdx.x, tid = threadIdx.x;
    int lo = 0, hi = NN;
    while (lo < hi){ int mid = (lo+hi)>>1; if (batch[mid] < g) lo = mid+1; else hi = mid; }
    int start = lo;
    lo = start; hi = NN;
    while (lo < hi){ int mid = (lo+hi)>>1; if (batch[mid] < g+1) lo = mid+1; else hi = mid; }
    int end = lo;
    __shared__ float red[225];
    if (tid < 225){
        int col = tid % 75, rep = tid / 75;
        float acc = 0.f;
        for (int i = start + rep; i < end; i += 3) acc += h[(size_t)i*75 + col];
        red[tid] = acc;
    }
    __syncthreads();
    if (tid < 75) gpool[g*75 + tid] = red[tid] + red[75+tid] + red[150+tid];
}

// 8 blocks x 8 graphs; weights in LDS, phase-parallel
__global__ __launch_bounds__(256) void k_mlp(const float* __restrict__ gpool,
        const float* __restrict__ W1, const float* __restrict__ b1,
        const float* __restrict__ W2, const float* __restrict__ b2,
        const float* __restrict__ W3, const float* __restrict__ b3,
        float* __restrict__ out){
    __shared__ float w1[75*50];
    __shared__ float w2[50*25];
    __shared__ float gp[8*75];
    __shared__ float t1[8*50];
    __shared__ float t2[8*25];
    int tid = threadIdx.x;
    int gbase = blockIdx.x*8;
    for (int i = tid; i < 75*50; i += 256) w1[i] = W1[i];
    for (int i = tid; i < 50*25; i += 256) w2[i] = W2[i];
    for (int i = tid; i < 8*75; i += 256) gp[i] = gpool[gbase*75 + i];
    __syncthreads();
    for (int task = tid; task < 8*50; task += 256){
        int g = task/50, j = task - 50*g;
        float s = b1[j];
        const float* gv = gp + g*75;
        #pragma unroll 5
        for (int k = 0; k < 75; k++) s += gv[k]*w1[k*50+j];
        t1[task] = s > 0.f ? s : 0.f;
    }
    __syncthreads();
    for (int task = tid; task < 8*25; task += 256){
        int g = task/25, j = task - 25*g;
        float s = b2[j];
        const float* tv = t1 + g*50;
        #pragma unroll 5
        for (int k = 0; k < 50; k++) s += tv[k]*w2[k*25+j];
        t2[task] = s > 0.f ? s : 0.f;
    }
    __syncthreads();
    if (tid < 8){
        float s = b3[0];
        const float* tv = t2 + tid*25;
        #pragma unroll
        for (int k = 0; k < 25; k++) s += tv[k]*W3[k];
        out[gbase + tid] = s;
    }
}

extern "C" void kernel_launch(void* const* d_in, const int* in_sizes, int n_in,
                              void* d_out, int out_size, void* d_ws, size_t ws_size,
                              hipStream_t stream){
    const int* x          = (const int*)d_in[0];
    const int* edge_index = (const int*)d_in[1];
    const int* edge_attr  = (const int*)d_in[2];
    const int* batch      = (const int*)d_in[3];
    const float* node_emb = (const float*)d_in[4];
    const float* edge_emb = (const float*)d_in[5];
    const float* pre_lin_W= (const float*)d_in[6];
    const float* pre_lin_b= (const float*)d_in[7];
    const float* encW     = (const float*)d_in[8];
    const float* encb     = (const float*)d_in[9];
    const float* preW     = (const float*)d_in[10];
    const float* preb     = (const float*)d_in[11];
    const float* postW    = (const float*)d_in[12];
    const float* postb    = (const float*)d_in[13];
    const float* linW     = (const float*)d_in[14];
    const float* linb     = (const float*)d_in[15];
    const float* bng      = (const float*)d_in[16];
    const float* bnb      = (const float*)d_in[17];
    const float* mlpW1    = (const float*)d_in[18];
    const float* mlpb1    = (const float*)d_in[19];
    const float* mlpW2    = (const float*)d_in[20];
    const float* mlpb2    = (const float*)d_in[21];
    const float* mlpW3    = (const float*)d_in[22];
    const float* mlpb3    = (const float*)d_in[23];

    float* ws = (float*)d_ws;
    float* h      = ws + OFF_H;
    float* hc     = ws + OFF_HC;
    __hip_bfloat16* P = (__hip_bfloat16*)(ws + OFF_P);
    __hip_bfloat16* Q = (__hip_bfloat16*)(ws + OFF_Q);
    __hip_bfloat16* agg = (__hip_bfloat16*)(ws + OFF_AGG);
    float* rlut4  = ws + OFF_RLUT4;
    float* invdeg = ws + OFF_INVDEG;
    float* amp    = ws + OFF_AMP;
    float* att    = ws + OFF_ATT;
    float* stats  = ws + OFF_STATS;   // 2 x 192 ping-pong
    float* gpool  = ws + OFF_GPOOL;
    __hip_bfloat16* postbase = (__hip_bfloat16*)(ws + OFF_P);  // bf16 partials z=0..6
    int* iw     = (int*)(ws + OFF_INT);
    int* cnt    = iw;
    int* eoff   = cnt + NN;        // NN+1
    int* cursor = eoff + NN + 2;
    int* esrc   = cursor + NN;
    int* ecombo = esrc + NE;

    k_zero_cnt<<<40, 256, 0, stream>>>(cnt);
    k_rlut4<<<dim3(5, 4), 384, 0, stream>>>(preW, preb, edge_emb, encW, encb, rlut4);
    k_h0<<<640, 256, 0, stream>>>(x, node_emb, pre_lin_W, pre_lin_b, h);
    k_hist<<<625, 256, 0, stream>>>(edge_index, cnt);
    k_scan<<<1, 256, 0, stream>>>(cnt, eoff);
    k_nodestats<<<40, 256, 0, stream>>>(cnt, eoff, invdeg, amp, att, cursor);
    k_scatter<<<625, 256, 0, stream>>>(edge_index, edge_attr, cursor, esrc, ecombo);

    for (int l = 0; l < NL; l++){
        k_pq<<<dim3(157, 12), 256, 0, stream>>>(h, hc, bng, bnb, preW, l, P, Q, stats);
        k_agg<<<dim3(6, NN), 64, 0, stream>>>(P, Q, rlut4 + (size_t)l*6000,
                                              eoff, esrc, ecombo, invdeg, agg,
                                              stats + (l & 1)*192);
        k_post<<<dim3(79, 5, 7), 256, 0, stream>>>(h, agg, postW, postb, amp, att, l, postbase);
        k_lin<<<625, 256, 0, stream>>>(postbase, linW, linb, l, hc, stats);
    }

    // final BN (layer 3) -> h, then pool + MLP
    k_bnapply<<<2930, 256, 0, stream>>>(hc, stats + ((NL-1)&1)*192, bng, bnb, NL-1, h);
    k_pool<<<NG, 256, 0, stream>>>(h, batch, gpool);
    k_mlp<<<8, 256, 0, stream>>>(gpool, mlpW1, mlpb1, mlpW2, mlpb2, mlpW3, mlpb3, (float*)d_out);
}

// Round 9
// 809.937 us; speedup vs baseline: 6.0326x; 1.0600x over previous
//
#include <hip/hip_runtime.h>
#include <hip/hip_bf16.h>
#include <math.h>

#define NN 10000
#define NE 160000
#define NG 64
#define NT 5
#define NL 4
#define ADL 2.833213344056216f

// ws layout (float offsets)
#define OFF_H      0
#define OFF_HC     750000
#define OFF_P      1500000     // bf16 P during agg; reused as bf16 post partials z=0..6
#define OFF_Q      5250000     // bf16 Q
#define OFF_AGG    9000000     // bf16 agg (15M bf16 = 7.5M floats, ends 16.5M)
#define OFF_RLUT4  16500000    // 4 layers x 6000 floats
#define OFF_INVDEG 24006000
#define OFF_AMP    24016000
#define OFF_ATT    24026000
#define OFF_STATS  24036000    // 2 ping-pong buffers x 192 floats
#define OFF_GPOOL  24040000
#define OFF_INT    24118960

typedef __attribute__((ext_vector_type(2))) unsigned int uv2;

__device__ __forceinline__ float bf2f(__hip_bfloat16 v){ return __bfloat162float(v); }

__global__ void k_zero_cnt(int* cnt){
    int i = blockIdx.x*256 + threadIdx.x;
    if (i < NN) cnt[i] = 0;
}

// h0 = node_emb[x].reshape(N,150) @ pre_lin_W + b
__global__ __launch_bounds__(256) void k_h0(const int* __restrict__ x,
        const float* __restrict__ node_emb, const float* __restrict__ plW,
        const float* __restrict__ plb, float* __restrict__ h){
    __shared__ float s_emb[21*75];
    __shared__ float s_W[150*75];
    __shared__ float s_b[75];
    int tid = threadIdx.x;
    for (int i = tid; i < 21*75; i += 256) s_emb[i] = node_emb[i];
    for (int i = tid; i < 150*75; i += 256) s_W[i] = plW[i];
    if (tid < 75) s_b[tid] = plb[tid];
    __syncthreads();
    for (int out = blockIdx.x*256 + tid; out < NN*75; out += gridDim.x*256){
        int n = out / 75, f = out - n*75;
        int x0 = x[2*n], x1 = x[2*n+1];
        float acc = s_b[f];
        const float* e0 = s_emb + x0*75;
        const float* e1 = s_emb + x1*75;
        #pragma unroll 5
        for (int k = 0; k < 75; k++)
            acc += e0[k]*s_W[k*75+f] + e1[k]*s_W[(75+k)*75+f];
        h[out] = acc;
    }
}

__global__ void k_hist(const int* __restrict__ ei, int* __restrict__ cnt){
    int e = blockIdx.x*256 + threadIdx.x;
    if (e < NE) atomicAdd(&cnt[ei[NE + e]], 1);
}

// single-block prefix sum: eoff[0]=0, eoff[n+1]=inclusive prefix
__global__ void k_scan(const int* __restrict__ cnt, int* __restrict__ eoff){
    __shared__ int buf[256];
    __shared__ int carry;
    int tid = threadIdx.x;
    if (tid == 0){ carry = 0; eoff[0] = 0; }
    __syncthreads();
    for (int base = 0; base < NN; base += 256){
        int v = (base + tid < NN) ? cnt[base + tid] : 0;
        buf[tid] = v; __syncthreads();
        for (int off = 1; off < 256; off <<= 1){
            int t2 = (tid >= off) ? buf[tid - off] : 0;
            __syncthreads();
            buf[tid] += t2;
            __syncthreads();
        }
        int inc = buf[tid] + carry;
        if (base + tid < NN) eoff[base + tid + 1] = inc;
        __syncthreads();
        if (tid == 255) carry = inc;
        __syncthreads();
    }
}

__global__ void k_nodestats(const int* __restrict__ cnt, const int* __restrict__ eoff,
        float* __restrict__ invdeg, float* __restrict__ amp, float* __restrict__ att,
        int* __restrict__ cursor){
    int n = blockIdx.x*256 + threadIdx.x;
    if (n >= NN) return;
    int c = cnt[n];
    cursor[n] = eoff[n];
    float cf = (float)c;
    float dg = cf < 1.f ? 1.f : cf;
    invdeg[n] = 1.f / dg;
    float ld = logf(dg + 1.f);
    amp[n] = ld / ADL;
    att[n] = ADL / ld;
}

__global__ void k_scatter(const int* __restrict__ ei, const int* __restrict__ ea,
        int* __restrict__ cursor, int* __restrict__ esrc, int* __restrict__ ecombo){
    int e = blockIdx.x*256 + threadIdx.x;
    if (e >= NE) return;
    int src = ei[e], dst = ei[NE + e];
    int pos = atomicAdd(&cursor[dst], 1);
    esrc[pos] = src;
    ecombo[pos] = ea[2*e]*4 + ea[2*e+1];
}

// R19: Rlut depends only on weights -> hoisted out of the layer loop.
// One launch, grid (5 towers, 4 layers).
__global__ __launch_bounds__(384) void k_rlut4(
        const float* __restrict__ preW, const float* __restrict__ preb,
        const float* __restrict__ edge_emb, const float* __restrict__ encW,
        const float* __restrict__ encb, float* __restrict__ rlut_all){
    __shared__ float smem[10675];
    int tid = threadIdx.x;
    int t = blockIdx.x;
    int l = blockIdx.y;
    float* s_encW = smem;            // 50*75 = 3750
    float* s_ev   = smem + 3750;     // 16*75 = 1200
    float* s_wc   = smem + 4950;     // 75*75 = 5625
    float* s_ee   = smem + 10575;    // 100
    for (int i = tid; i < 3750; i += 384) s_encW[i] = encW[(size_t)l*3750 + i];
    for (int i = tid; i < 100; i += 384) s_ee[i] = edge_emb[i];
    const float* wcsrc = preW + (((size_t)(l*NT + t))*225 + 150)*75;
    for (int i = tid; i < 5625; i += 384) s_wc[i] = wcsrc[i];
    __syncthreads();
    for (int task = tid; task < 1200; task += 384){
        int b = task/75, m = task - 75*b;
        int a0 = b >> 2, a1 = b & 3;
        float s = encb[l*75 + m];
        for (int k = 0; k < 25; k++)
            s += s_ee[a0*25+k]*s_encW[k*75+m] + s_ee[a1*25+k]*s_encW[(25+k)*75+m];
        s_ev[task] = s;
    }
    __syncthreads();
    for (int task = tid; task < 1200; task += 384){
        int b = task/75, f = task - 75*b;
        float r = preb[((size_t)l*NT + t)*75 + f];
        const float* ev = s_ev + b*75;
        #pragma unroll 5
        for (int m = 0; m < 75; m++) r += ev[m]*s_wc[m*75 + f];
        rlut_all[(size_t)l*6000 + b*375 + t*75 + f] = r;
    }
}

// R25: k_pq = R4 structure with a 64-node x 128-col tile computed as two
// sequential 64-col halves sharing ONE staged h-tile. Same LDS (38.9 KB ->
// 4 blocks/CU, the binding constraint per R7) and same per-half inner loop;
// h-tile staged/fetched by 6 blocks instead of 12 (raw h traffic halves,
// l>0 BN recompute 12x -> 6x), per-thread FMA doubles for latency hiding.
// Barriers: stage(h,w0); sync; compute0+store0; sync; stage(w1); sync;
// compute1+store1.  grid (157, 6).
__global__ __launch_bounds__(256, 4) void k_pq(float* __restrict__ h,
        const float* __restrict__ hc, const float* __restrict__ bng,
        const float* __restrict__ bnb,
        const float* __restrict__ preW,
        int l, __hip_bfloat16* __restrict__ P, __hip_bfloat16* __restrict__ Q,
        const float* __restrict__ stats_all){
    __shared__ float s_h[64*76];   // node-major, col 75 = 0 pad
    __shared__ float s_w[76*64];   // k-major, row 75 = 0 pad
    int tid = threadIdx.x;
    int base_n = blockIdx.x*64;
    int tx = tid & 15;             // col group (4 cols)
    int ty = tid >> 4;             // node group (4 nodes)

    // stage h tile (l>0: BN+ReLU from previous layer, write-back once)
    if (l == 0){
        for (int idx = tid; idx < 64*76; idx += 256){
            int i = idx/76, m = idx - 76*i;
            int n = base_n + i;
            s_h[idx] = (m < 75 && n < NN) ? h[(size_t)n*75 + m] : 0.f;
        }
    } else {
        const float* stats_rd = stats_all + ((l + 1) & 1)*192;
        int lp = l - 1;
        for (int idx = tid; idx < 64*76; idx += 256){
            int i = idx/76, m = idx - 76*i;
            int n = base_n + i;
            float v = 0.f;
            if (m < 75 && n < NN){
                float mu = stats_rd[m]*(1.0f/NN);
                float var = stats_rd[75+m]*(1.0f/NN) - mu*mu;
                float inv = rsqrtf(var + 1e-5f);
                v = (hc[(size_t)n*75 + m] - mu)*inv*bng[lp*75+m] + bnb[lp*75+m];
                v = v > 0.f ? v : 0.f;
                if (blockIdx.y == 0) h[(size_t)n*75 + m] = v;
            }
            s_h[idx] = v;
        }
    }

    for (int half = 0; half < 2; half++){
        int base_c = blockIdx.y*128 + half*64;
        if (half){
            __syncthreads();   // all reads of s_w (half 0) complete
        }
        // stage W tile: k-major, wave lanes cover 64 consecutive cols -> coalesced
        for (int idx = tid; idx < 76*64; idx += 256){
            int k = idx >> 6, c = idx & 63;
            int col = base_c + c;
            float v = 0.f;
            if (k < 75 && col < 750){
                int cc2 = col < 375 ? col : col - 375;
                int t = cc2/75, f = cc2 - t*75;
                int ro = col < 375 ? 0 : 75;
                v = preW[(((size_t)(l*NT + t))*225 + ro + k)*75 + f];
            }
            s_w[idx] = v;
        }
        __syncthreads();

        float acc[4][4] = {};
        const float* hrow = s_h + (ty*4)*76;
        const float* wrow = s_w + tx*4;
        for (int k4 = 0; k4 < 76; k4 += 4){
            float4 hv[4], wv[4];
            #pragma unroll
            for (int r = 0; r < 4; r++)
                hv[r] = *(const float4*)(hrow + r*76 + k4);
            #pragma unroll
            for (int kk = 0; kk < 4; kk++)
                wv[kk] = *(const float4*)(wrow + (k4+kk)*64);
            #pragma unroll
            for (int r = 0; r < 4; r++){
                float h0 = hv[r].x, h1 = hv[r].y, h2 = hv[r].z, h3 = hv[r].w;
                acc[r][0] += h0*wv[0].x + h1*wv[1].x + h2*wv[2].x + h3*wv[3].x;
                acc[r][1] += h0*wv[0].y + h1*wv[1].y + h2*wv[2].y + h3*wv[3].y;
                acc[r][2] += h0*wv[0].z + h1*wv[1].z + h2*wv[2].z + h3*wv[3].z;
                acc[r][3] += h0*wv[0].w + h1*wv[1].w + h2*wv[2].w + h3*wv[3].w;
            }
        }

        #pragma unroll
        for (int r = 0; r < 4; r++){
            int n = base_n + ty*4 + r;
            if (n >= NN) continue;
            #pragma unroll
            for (int cc = 0; cc < 4; cc++){
                int c = base_c + tx*4 + cc;
                if (c >= 750) continue;
                __hip_bfloat16 v = __float2bfloat16(acc[r][cc]);
                if (c < 375) P[(size_t)n*375 + c] = v;
                else         Q[(size_t)n*375 + (c - 375)] = v;
            }
        }
    }
}

// grid (6, NN), block 64. bf16 Q gather; edge loop unrolled x8.
// R20: block (0,0) additionally zeros the BN-stats buffer for this layer
// (runs before k_lin's atomicAdds via stream ordering).
__global__ __launch_bounds__(64) void k_agg(const __hip_bfloat16* __restrict__ P,
        const __hip_bfloat16* __restrict__ Q, const float* __restrict__ Rlut,
        const int* __restrict__ eoff, const int* __restrict__ esrc,
        const int* __restrict__ ecombo, const float* __restrict__ invdeg,
        __hip_bfloat16* __restrict__ agg, float* __restrict__ stats_zero){
    int n = blockIdx.y;
    int j = blockIdx.x*64 + threadIdx.x;
    if (blockIdx.x == 0 && n == 0){
        for (int i = threadIdx.x; i < 150; i += 64) stats_zero[i] = 0.f;
    }
    if (j >= 375) return;
    int lo = eoff[n], hi = eoff[n+1];
    float p = bf2f(P[(size_t)n*375 + j]);
    float sum = 0.f, sq = 0.f, mn = 3.4e38f, mx = -3.4e38f;
    int e = lo;
    for (; e + 8 <= hi; e += 8){
        int s0 = esrc[e],   s1 = esrc[e+1], s2 = esrc[e+2], s3 = esrc[e+3];
        int s4 = esrc[e+4], s5 = esrc[e+5], s6 = esrc[e+6], s7 = esrc[e+7];
        int c0 = ecombo[e],   c1 = ecombo[e+1], c2 = ecombo[e+2], c3 = ecombo[e+3];
        int c4 = ecombo[e+4], c5 = ecombo[e+5], c6 = ecombo[e+6], c7 = ecombo[e+7];
        float q0 = bf2f(Q[(size_t)s0*375 + j]);
        float q1 = bf2f(Q[(size_t)s1*375 + j]);
        float q2 = bf2f(Q[(size_t)s2*375 + j]);
        float q3 = bf2f(Q[(size_t)s3*375 + j]);
        float q4 = bf2f(Q[(size_t)s4*375 + j]);
        float q5 = bf2f(Q[(size_t)s5*375 + j]);
        float q6 = bf2f(Q[(size_t)s6*375 + j]);
        float q7 = bf2f(Q[(size_t)s7*375 + j]);
        float r0 = Rlut[c0*375 + j], r1 = Rlut[c1*375 + j];
        float r2 = Rlut[c2*375 + j], r3 = Rlut[c3*375 + j];
        float r4 = Rlut[c4*375 + j], r5 = Rlut[c5*375 + j];
        float r6 = Rlut[c6*375 + j], r7 = Rlut[c7*375 + j];
        float m0 = p + q0 + r0, m1 = p + q1 + r1;
        float m2 = p + q2 + r2, m3 = p + q3 + r3;
        float m4 = p + q4 + r4, m5 = p + q5 + r5;
        float m6 = p + q6 + r6, m7 = p + q7 + r7;
        sum += (m0 + m1 + m2 + m3) + (m4 + m5 + m6 + m7);
        sq  += (m0*m0 + m1*m1 + m2*m2 + m3*m3) + (m4*m4 + m5*m5 + m6*m6 + m7*m7);
        mn = fminf(mn, fminf(fminf(fminf(m0,m1), fminf(m2,m3)),
                             fminf(fminf(m4,m5), fminf(m6,m7))));
        mx = fmaxf(mx, fmaxf(fmaxf(fmaxf(m0,m1), fmaxf(m2,m3)),
                             fmaxf(fmaxf(m4,m5), fmaxf(m6,m7))));
    }
    for (; e < hi; e++){
        int s = esrc[e], cm = ecombo[e];
        float m = p + bf2f(Q[(size_t)s*375 + j]) + Rlut[cm*375 + j];
        sum += m; sq += m*m;
        mn = fminf(mn, m); mx = fmaxf(mx, m);
    }
    float id = invdeg[n];
    bool has = hi > lo;
    float mean = sum*id;
    float msq  = sq*id;
    float var = msq - mean*mean; var = var > 0.f ? var : 0.f;
    float sd = sqrtf(var + 1e-5f);
    float mnv = has ? mn : 0.f;
    float mxv = has ? mx : 0.f;
    int t = j/75, f = j - 75*t;
    __hip_bfloat16* a = agg + ((size_t)n*NT + t)*300;
    a[f]      = __float2bfloat16(mean);
    a[75+f]   = __float2bfloat16(mnv);
    a[150+f]  = __float2bfloat16(mxv);
    a[225+f]  = __float2bfloat16(sd);
}

// post einsum, barrier-free; bf16 partials. grid (79, 5, 7).
// R19: 128-node tile: LDS 22.9 KB, 2765 blocks for smoother CU packing.
// R17 LDS staging retained: agg tile stride 52 ushorts, conflict-free.
#define KB2 50
__global__ __launch_bounds__(256, 6) void k_post(const float* __restrict__ h,
        const __hip_bfloat16* __restrict__ agg, const float* __restrict__ postW,
        const float* __restrict__ postb, const float* __restrict__ amp,
        const float* __restrict__ att, int l, __hip_bfloat16* __restrict__ postbase){
    __shared__ float s_w[3*KB2*16];              // 9.6 KB (z0 uses first 75*16=1200)
    __shared__ unsigned short s_a[128*52];       // 13.3 KB agg tile
    int t = blockIdx.y;
    int z = blockIdx.z;
    int nbase = blockIdx.x*128;
    int tid = threadIdx.x;
    int fg  = (tid & 3)*4;
    int sub = tid >> 2;
    const float* Wt = postW + ((size_t)(l*NT + t))*975*15;

    if (z == 0){
        for (int idx = tid; idx < 75*16; idx += 256){
            int c = idx >> 4, f = idx & 15;
            s_w[idx] = (f < 15) ? Wt[c*15 + f] : 0.f;
        }
        __syncthreads();
        float a1[2][4] = {};
        const float* hrow[2];
        #pragma unroll
        for (int j = 0; j < 2; j++){
            int n = nbase + sub + 64*j;
            hrow[j] = h + (size_t)(n < NN ? n : 0)*75;
        }
        #pragma unroll 3
        for (int k = 0; k < 75; k++){
            const float4 w1 = *(const float4*)&s_w[k*16 + fg];
            #pragma unroll
            for (int j = 0; j < 2; j++){
                float v = hrow[j][k];
                a1[j][0] += v*w1.x; a1[j][1] += v*w1.y;
                a1[j][2] += v*w1.z; a1[j][3] += v*w1.w;
            }
        }
        const float* pb = postb + (l*NT + t)*15;
        #pragma unroll
        for (int j = 0; j < 2; j++){
            int n = nbase + sub + 64*j;
            if (n >= NN) continue;
            __hip_bfloat16* dst = postbase + (size_t)n*75 + t*15;
            #pragma unroll
            for (int f = 0; f < 4; f++)
                if (fg + f < 15) dst[fg + f] = __float2bfloat16(a1[j][f] + pb[fg + f]);
        }
        return;
    }

    int kbeg = (z-1)*KB2;
    // stage weights
    for (int idx = tid; idx < 3*KB2*16; idx += 256){
        int vrow = idx / (KB2*16);
        int rem = idx - vrow*(KB2*16);
        int c = rem >> 4, f = rem & 15;
        s_w[idx] = (f < 15) ? Wt[(75 + vrow*300 + kbeg + c)*15 + f] : 0.f;
    }
    // stage agg tile: node i's 50 bf16 slice = 25 dwords, contiguous 100B runs
    {
        const unsigned short* asrc = (const unsigned short*)agg;
        for (int idx = tid; idx < 128*25; idx += 256){
            int i = idx/25, w = idx - 25*i;
            int n = nbase + i;
            unsigned int u = 0;
            if (n < NN)
                u = *(const unsigned int*)(asrc + (size_t)n*1500 + t*300 + kbeg + 2*w);
            *(unsigned int*)&s_a[i*52 + 2*w] = u;
        }
    }
    __syncthreads();

    float a1[2][4] = {}, a2[2][4] = {}, a3[2][4] = {};
    const unsigned short* ap0 = s_a + sub*52;
    #pragma unroll 2
    for (int k4 = 0; k4 < 48; k4 += 4){
        uv2 ua[2];
        #pragma unroll
        for (int j = 0; j < 2; j++)
            ua[j] = *(const uv2*)(ap0 + j*(64*52) + k4);
        #pragma unroll
        for (int kk = 0; kk < 4; kk++){
            int k = k4 + kk;
            const float4 w1 = *(const float4*)&s_w[k*16 + fg];
            const float4 w2 = *(const float4*)&s_w[(KB2 + k)*16 + fg];
            const float4 w3 = *(const float4*)&s_w[(2*KB2 + k)*16 + fg];
            #pragma unroll
            for (int j = 0; j < 2; j++){
                unsigned int bits = (kk < 2) ? ua[j].x : ua[j].y;
                float v = __uint_as_float((kk & 1) ? (bits & 0xffff0000u)
                                                   : (bits << 16));
                a1[j][0] += v*w1.x; a1[j][1] += v*w1.y;
                a1[j][2] += v*w1.z; a1[j][3] += v*w1.w;
                a2[j][0] += v*w2.x; a2[j][1] += v*w2.y;
                a2[j][2] += v*w2.z; a2[j][3] += v*w2.w;
                a3[j][0] += v*w3.x; a3[j][1] += v*w3.y;
                a3[j][2] += v*w3.z; a3[j][3] += v*w3.w;
            }
        }
    }
    // tail k = 48, 49 (one dword per row)
    {
        unsigned int ut[2];
        #pragma unroll
        for (int j = 0; j < 2; j++)
            ut[j] = *(const unsigned int*)(ap0 + j*(64*52) + 48);
        #pragma unroll
        for (int kk = 0; kk < 2; kk++){
            int k = 48 + kk;
            const float4 w1 = *(const float4*)&s_w[k*16 + fg];
            const float4 w2 = *(const float4*)&s_w[(KB2 + k)*16 + fg];
            const float4 w3 = *(const float4*)&s_w[(2*KB2 + k)*16 + fg];
            #pragma unroll
            for (int j = 0; j < 2; j++){
                float v = __uint_as_float((kk & 1) ? (ut[j] & 0xffff0000u)
                                                   : (ut[j] << 16));
                a1[j][0] += v*w1.x; a1[j][1] += v*w1.y;
                a1[j][2] += v*w1.z; a1[j][3] += v*w1.w;
                a2[j][0] += v*w2.x; a2[j][1] += v*w2.y;
                a2[j][2] += v*w2.z; a2[j][3] += v*w2.w;
                a3[j][0] += v*w3.x; a3[j][1] += v*w3.y;
                a3[j][2] += v*w3.z; a3[j][3] += v*w3.w;
            }
        }
    }
    __hip_bfloat16* postv = postbase + (size_t)z*750000;
    #pragma unroll
    for (int j = 0; j < 2; j++){
        int n = nbase + sub + 64*j;
        if (n >= NN) continue;
        float am = amp[n], at = att[n];
        __hip_bfloat16* dst = postv + (size_t)n*75 + t*15;
        #pragma unroll
        for (int f = 0; f < 4; f++)
            if (fg + f < 15)
                dst[fg + f] = __float2bfloat16(a1[j][f] + am*a2[j][f] + at*a3[j][f]);
    }
}

// hc = (Σz postz) @ lin_W[l] + lin_b[l]; fused BN-stat reduction into buffer l&1.
// R25: reverted to the R4 geometry (32 nodes x 313 blocks) — R8's 16x625
// split was a measured ~14 us total regression (doubled linW staging).
__global__ __launch_bounds__(256) void k_lin(const __hip_bfloat16* __restrict__ postbase,
        const float* __restrict__ linW, const float* __restrict__ linb,
        int l, float* __restrict__ hc, float* __restrict__ stats_all){
    __shared__ float p_l[32*75];
    __shared__ float w_l[75*75];
    __shared__ float hc_l[32*75];
    int tid = threadIdx.x;
    int base = blockIdx.x*32;
    for (int i = tid; i < 75*75; i += 256) w_l[i] = linW[(size_t)l*5625 + i];
    for (int i = tid; i < 32*75; i += 256){
        int n = base + i/75;
        size_t idx = (size_t)base*75 + i;
        float v = 0.f;
        if (n < NN){
            #pragma unroll
            for (int z = 0; z < 7; z++) v += bf2f(postbase[idx + (size_t)z*750000]);
        }
        p_l[i] = v;
    }
    __syncthreads();
    for (int task = tid; task < 2400; task += 256){
        int i = task/75, o = task - 75*i;
        float s = linb[l*75 + o];
        const float* pl = p_l + i*75;
        #pragma unroll 5
        for (int j = 0; j < 75; j++) s += pl[j]*w_l[j*75 + o];
        hc_l[task] = s;
        if (base + i < NN) hc[(size_t)(base+i)*75 + o] = s;
    }
    __syncthreads();
    if (tid < 75){
        float* stats_wr = stats_all + (l & 1)*192;
        int nv = NN - base; if (nv > 32) nv = 32;
        float s1 = 0.f, s2 = 0.f;
        for (int i = 0; i < nv; i++){
            float v = hc_l[i*75 + tid];
            s1 += v; s2 += v*v;
        }
        atomicAdd(&stats_wr[tid], s1);
        atomicAdd(&stats_wr[75+tid], s2);
    }
}

// final BN apply (only after last layer; earlier layers fused into k_pq)
__global__ void k_bnapply(const float* __restrict__ hc, const float* __restrict__ stats,
        const float* __restrict__ bng, const float* __restrict__ bnb, int l,
        float* __restrict__ h){
    int idx = blockIdx.x*256 + threadIdx.x;
    if (idx >= NN*75) return;
    int col = idx % 75;
    float mu = stats[col]*(1.0f/NN);
    float var = stats[75+col]*(1.0f/NN) - mu*mu;
    float inv = rsqrtf(var + 1e-5f);
    float v = (hc[idx] - mu)*inv*bng[l*75+col] + bnb[l*75+col];
    h[idx] = v > 0.f ? v : 0.f;
}

__global__ __launch_bounds__(256) void k_pool(const float* __restrict__ h,
        const int* __restrict__ batch, float* __restrict__ gpool){
    int g = blockIdx.x, tid = threadIdx.x;
    int lo = 0, hi = NN;
    while (lo < hi){ int mid = (lo+hi)>>1; if (batch[mid] < g) lo = mid+1; else hi = mid; }
    int start = lo;
    lo = start; hi = NN;
    while (lo < hi){ int mid = (lo+hi)>>1; if (batch[mid] < g+1) lo = mid+1; else hi = mid; }
    int end = lo;
    __shared__ float red[225];
    if (tid < 225){
        int col = tid % 75, rep = tid / 75;
        float acc = 0.f;
        for (int i = start + rep; i < end; i += 3) acc += h[(size_t)i*75 + col];
        red[tid] = acc;
    }
    __syncthreads();
    if (tid < 75) gpool[g*75 + tid] = red[tid] + red[75+tid] + red[150+tid];
}

// 8 blocks x 8 graphs; weights in LDS, phase-parallel
__global__ __launch_bounds__(256) void k_mlp(const float* __restrict__ gpool,
        const float* __restrict__ W1, const float* __restrict__ b1,
        const float* __restrict__ W2, const float* __restrict__ b2,
        const float* __restrict__ W3, const float* __restrict__ b3,
        float* __restrict__ out){
    __shared__ float w1[75*50];
    __shared__ float w2[50*25];
    __shared__ float gp[8*75];
    __shared__ float t1[8*50];
    __shared__ float t2[8*25];
    int tid = threadIdx.x;
    int gbase = blockIdx.x*8;
    for (int i = tid; i < 75*50; i += 256) w1[i] = W1[i];
    for (int i = tid; i < 50*25; i += 256) w2[i] = W2[i];
    for (int i = tid; i < 8*75; i += 256) gp[i] = gpool[gbase*75 + i];
    __syncthreads();
    for (int task = tid; task < 8*50; task += 256){
        int g = task/50, j = task - 50*g;
        float s = b1[j];
        const float* gv = gp + g*75;
        #pragma unroll 5
        for (int k = 0; k < 75; k++) s += gv[k]*w1[k*50+j];
        t1[task] = s > 0.f ? s : 0.f;
    }
    __syncthreads();
    for (int task = tid; task < 8*25; task += 256){
        int g = task/25, j = task - 25*g;
        float s = b2[j];
        const float* tv = t1 + g*50;
        #pragma unroll 5
        for (int k = 0; k < 50; k++) s += tv[k]*w2[k*25+j];
        t2[task] = s > 0.f ? s : 0.f;
    }
    __syncthreads();
    if (tid < 8){
        float s = b3[0];
        const float* tv = t2 + tid*25;
        #pragma unroll
        for (int k = 0; k < 25; k++) s += tv[k]*W3[k];
        out[gbase + tid] = s;
    }
}

extern "C" void kernel_launch(void* const* d_in, const int* in_sizes, int n_in,
                              void* d_out, int out_size, void* d_ws, size_t ws_size,
                              hipStream_t stream){
    const int* x          = (const int*)d_in[0];
    const int* edge_index = (const int*)d_in[1];
    const int* edge_attr  = (const int*)d_in[2];
    const int* batch      = (const int*)d_in[3];
    const float* node_emb = (const float*)d_in[4];
    const float* edge_emb = (const float*)d_in[5];
    const float* pre_lin_W= (const float*)d_in[6];
    const float* pre_lin_b= (const float*)d_in[7];
    const float* encW     = (const float*)d_in[8];
    const float* encb     = (const float*)d_in[9];
    const float* preW     = (const float*)d_in[10];
    const float* preb     = (const float*)d_in[11];
    const float* postW    = (const float*)d_in[12];
    const float* postb    = (const float*)d_in[13];
    const float* linW     = (const float*)d_in[14];
    const float* linb     = (const float*)d_in[15];
    const float* bng      = (const float*)d_in[16];
    const float* bnb      = (const float*)d_in[17];
    const float* mlpW1    = (const float*)d_in[18];
    const float* mlpb1    = (const float*)d_in[19];
    const float* mlpW2    = (const float*)d_in[20];
    const float* mlpb2    = (const float*)d_in[21];
    const float* mlpW3    = (const float*)d_in[22];
    const float* mlpb3    = (const float*)d_in[23];

    float* ws = (float*)d_ws;
    float* h      = ws + OFF_H;
    float* hc     = ws + OFF_HC;
    __hip_bfloat16* P = (__hip_bfloat16*)(ws + OFF_P);
    __hip_bfloat16* Q = (__hip_bfloat16*)(ws + OFF_Q);
    __hip_bfloat16* agg = (__hip_bfloat16*)(ws + OFF_AGG);
    float* rlut4  = ws + OFF_RLUT4;
    float* invdeg = ws + OFF_INVDEG;
    float* amp    = ws + OFF_AMP;
    float* att    = ws + OFF_ATT;
    float* stats  = ws + OFF_STATS;   // 2 x 192 ping-pong
    float* gpool  = ws + OFF_GPOOL;
    __hip_bfloat16* postbase = (__hip_bfloat16*)(ws + OFF_P);  // bf16 partials z=0..6
    int* iw     = (int*)(ws + OFF_INT);
    int* cnt    = iw;
    int* eoff   = cnt + NN;        // NN+1
    int* cursor = eoff + NN + 2;
    int* esrc   = cursor + NN;
    int* ecombo = esrc + NE;

    k_zero_cnt<<<40, 256, 0, stream>>>(cnt);
    k_rlut4<<<dim3(5, 4), 384, 0, stream>>>(preW, preb, edge_emb, encW, encb, rlut4);
    k_h0<<<640, 256, 0, stream>>>(x, node_emb, pre_lin_W, pre_lin_b, h);
    k_hist<<<625, 256, 0, stream>>>(edge_index, cnt);
    k_scan<<<1, 256, 0, stream>>>(cnt, eoff);
    k_nodestats<<<40, 256, 0, stream>>>(cnt, eoff, invdeg, amp, att, cursor);
    k_scatter<<<625, 256, 0, stream>>>(edge_index, edge_attr, cursor, esrc, ecombo);

    for (int l = 0; l < NL; l++){
        k_pq<<<dim3(157, 6), 256, 0, stream>>>(h, hc, bng, bnb, preW, l, P, Q, stats);
        k_agg<<<dim3(6, NN), 64, 0, stream>>>(P, Q, rlut4 + (size_t)l*6000,
                                              eoff, esrc, ecombo, invdeg, agg,
                                              stats + (l & 1)*192);
        k_post<<<dim3(79, 5, 7), 256, 0, stream>>>(h, agg, postW, postb, amp, att, l, postbase);
        k_lin<<<313, 256, 0, stream>>>(postbase, linW, linb, l, hc, stats);
    }

    // final BN (layer 3) -> h, then pool + MLP
    k_bnapply<<<2930, 256, 0, stream>>>(hc, stats + ((NL-1)&1)*192, bng, bnb, NL-1, h);
    k_pool<<<NG, 256, 0, stream>>>(h, batch, gpool);
    k_mlp<<<8, 256, 0, stream>>>(gpool, mlpW1, mlpb1, mlpW2, mlpb2, mlpW3, mlpb3, (float*)d_out);
}

// Round 10
// 782.671 us; speedup vs baseline: 6.2428x; 1.0348x over previous
//
#include <hip/hip_runtime.h>
#include <hip/hip_bf16.h>
#include <math.h>

#define NN 10000
#define NE 160000
#define NG 64
#define NT 5
#define NL 4
#define ADL 2.833213344056216f

// ws layout (float offsets)
#define OFF_H      0
#define OFF_HC     750000
#define OFF_P      1500000     // bf16 P during agg; reused as bf16 post partials z=0..6
#define OFF_Q      5250000     // bf16 Q
#define OFF_AGG    9000000     // bf16 agg (15M bf16 = 7.5M floats, ends 16.5M)
#define OFF_RLUT4  16500000    // 4 layers x 6000 floats
#define OFF_INVDEG 24006000
#define OFF_AMP    24016000
#define OFF_ATT    24026000
#define OFF_STATS  24036000    // 2 ping-pong buffers x 192 floats
#define OFF_GPOOL  24040000
#define OFF_INT    24118960

typedef __attribute__((ext_vector_type(2))) unsigned int uv2;

__device__ __forceinline__ float bf2f(__hip_bfloat16 v){ return __bfloat162float(v); }

__global__ void k_zero_cnt(int* cnt){
    int i = blockIdx.x*256 + threadIdx.x;
    if (i < NN) cnt[i] = 0;
}

// h0 = node_emb[x].reshape(N,150) @ pre_lin_W + b
__global__ __launch_bounds__(256) void k_h0(const int* __restrict__ x,
        const float* __restrict__ node_emb, const float* __restrict__ plW,
        const float* __restrict__ plb, float* __restrict__ h){
    __shared__ float s_emb[21*75];
    __shared__ float s_W[150*75];
    __shared__ float s_b[75];
    int tid = threadIdx.x;
    for (int i = tid; i < 21*75; i += 256) s_emb[i] = node_emb[i];
    for (int i = tid; i < 150*75; i += 256) s_W[i] = plW[i];
    if (tid < 75) s_b[tid] = plb[tid];
    __syncthreads();
    for (int out = blockIdx.x*256 + tid; out < NN*75; out += gridDim.x*256){
        int n = out / 75, f = out - n*75;
        int x0 = x[2*n], x1 = x[2*n+1];
        float acc = s_b[f];
        const float* e0 = s_emb + x0*75;
        const float* e1 = s_emb + x1*75;
        #pragma unroll 5
        for (int k = 0; k < 75; k++)
            acc += e0[k]*s_W[k*75+f] + e1[k]*s_W[(75+k)*75+f];
        h[out] = acc;
    }
}

__global__ void k_hist(const int* __restrict__ ei, int* __restrict__ cnt){
    int e = blockIdx.x*256 + threadIdx.x;
    if (e < NE) atomicAdd(&cnt[ei[NE + e]], 1);
}

// R26: single-pass block scan, 1024 threads x 10 nodes each, fused nodestats.
// R9 counters: old 256-thread Hillis-Steele version = 43.8 us (640 serial
// barriers on one CU, VALUBusy 0.01%). New: serial register prefix per thread,
// 64-lane shfl_up wave scan, 16 wave sums scanned by tid 0, 2 barriers total.
// Also computes cursor/invdeg/amp/att inline (replaces k_nodestats launch).
__global__ __launch_bounds__(1024) void k_scan(const int* __restrict__ cnt,
        int* __restrict__ eoff, float* __restrict__ invdeg,
        float* __restrict__ amp, float* __restrict__ att,
        int* __restrict__ cursor){
    __shared__ int wsum[16];
    int tid = threadIdx.x;
    int base = tid*10;               // 1024*10 = 10240 >= NN
    int v[10];
    int s = 0;
    #pragma unroll
    for (int i = 0; i < 10; i++){
        int n = base + i;
        int c = (n < NN) ? cnt[n] : 0;
        v[i] = s;                    // exclusive prefix within chunk
        s += c;
    }
    int lane = tid & 63;
    int wave = tid >> 6;             // 0..15
    int inc = s;
    #pragma unroll
    for (int off = 1; off < 64; off <<= 1){
        int t = __shfl_up(inc, off);
        if (lane >= off) inc += t;
    }
    if (lane == 63) wsum[wave] = inc;
    __syncthreads();
    if (tid == 0){
        int acc = 0;
        #pragma unroll
        for (int w = 0; w < 16; w++){ int t = wsum[w]; wsum[w] = acc; acc += t; }
        eoff[0] = 0;
    }
    __syncthreads();
    int ex = inc - s + wsum[wave];   // exclusive prefix at chunk start
    #pragma unroll
    for (int i = 0; i < 10; i++){
        int n = base + i;
        if (n < NN){
            int c = cnt[n];
            int start = ex + v[i];
            eoff[n+1] = start + c;
            cursor[n] = start;
            float cf = (float)c;
            float dg = cf < 1.f ? 1.f : cf;
            invdeg[n] = 1.f / dg;
            float ld = logf(dg + 1.f);
            amp[n] = ld / ADL;
            att[n] = ADL / ld;
        }
    }
}

__global__ void k_scatter(const int* __restrict__ ei, const int* __restrict__ ea,
        int* __restrict__ cursor, int* __restrict__ esrc, int* __restrict__ ecombo){
    int e = blockIdx.x*256 + threadIdx.x;
    if (e >= NE) return;
    int src = ei[e], dst = ei[NE + e];
    int pos = atomicAdd(&cursor[dst], 1);
    esrc[pos] = src;
    ecombo[pos] = ea[2*e]*4 + ea[2*e+1];
}

// R19: Rlut depends only on weights -> hoisted out of the layer loop.
// One launch, grid (5 towers, 4 layers).
__global__ __launch_bounds__(384) void k_rlut4(
        const float* __restrict__ preW, const float* __restrict__ preb,
        const float* __restrict__ edge_emb, const float* __restrict__ encW,
        const float* __restrict__ encb, float* __restrict__ rlut_all){
    __shared__ float smem[10675];
    int tid = threadIdx.x;
    int t = blockIdx.x;
    int l = blockIdx.y;
    float* s_encW = smem;            // 50*75 = 3750
    float* s_ev   = smem + 3750;     // 16*75 = 1200
    float* s_wc   = smem + 4950;     // 75*75 = 5625
    float* s_ee   = smem + 10575;    // 100
    for (int i = tid; i < 3750; i += 384) s_encW[i] = encW[(size_t)l*3750 + i];
    for (int i = tid; i < 100; i += 384) s_ee[i] = edge_emb[i];
    const float* wcsrc = preW + (((size_t)(l*NT + t))*225 + 150)*75;
    for (int i = tid; i < 5625; i += 384) s_wc[i] = wcsrc[i];
    __syncthreads();
    for (int task = tid; task < 1200; task += 384){
        int b = task/75, m = task - 75*b;
        int a0 = b >> 2, a1 = b & 3;
        float s = encb[l*75 + m];
        for (int k = 0; k < 25; k++)
            s += s_ee[a0*25+k]*s_encW[k*75+m] + s_ee[a1*25+k]*s_encW[(25+k)*75+m];
        s_ev[task] = s;
    }
    __syncthreads();
    for (int task = tid; task < 1200; task += 384){
        int b = task/75, f = task - 75*b;
        float r = preb[((size_t)l*NT + t)*75 + f];
        const float* ev = s_ev + b*75;
        #pragma unroll 5
        for (int m = 0; m < 75; m++) r += ev[m]*s_wc[m*75 + f];
        rlut_all[(size_t)l*6000 + b*375 + t*75 + f] = r;
    }
}

// R25: k_pq = R4 structure with a 64-node x 128-col tile computed as two
// sequential 64-col halves sharing ONE staged h-tile. Same LDS (38.9 KB ->
// 4 blocks/CU, the binding constraint per R7) and same per-half inner loop;
// h-tile staged/fetched by 6 blocks instead of 12 (raw h traffic halves,
// l>0 BN recompute 12x -> 6x), per-thread FMA doubles for latency hiding.
// Barriers: stage(h,w0); sync; compute0+store0; sync; stage(w1); sync;
// compute1+store1.  grid (157, 6).  [R9: verified winner, k_pq left top-5]
__global__ __launch_bounds__(256, 4) void k_pq(float* __restrict__ h,
        const float* __restrict__ hc, const float* __restrict__ bng,
        const float* __restrict__ bnb,
        const float* __restrict__ preW,
        int l, __hip_bfloat16* __restrict__ P, __hip_bfloat16* __restrict__ Q,
        const float* __restrict__ stats_all){
    __shared__ float s_h[64*76];   // node-major, col 75 = 0 pad
    __shared__ float s_w[76*64];   // k-major, row 75 = 0 pad
    int tid = threadIdx.x;
    int base_n = blockIdx.x*64;
    int tx = tid & 15;             // col group (4 cols)
    int ty = tid >> 4;             // node group (4 nodes)

    // stage h tile (l>0: BN+ReLU from previous layer, write-back once)
    if (l == 0){
        for (int idx = tid; idx < 64*76; idx += 256){
            int i = idx/76, m = idx - 76*i;
            int n = base_n + i;
            s_h[idx] = (m < 75 && n < NN) ? h[(size_t)n*75 + m] : 0.f;
        }
    } else {
        const float* stats_rd = stats_all + ((l + 1) & 1)*192;
        int lp = l - 1;
        for (int idx = tid; idx < 64*76; idx += 256){
            int i = idx/76, m = idx - 76*i;
            int n = base_n + i;
            float v = 0.f;
            if (m < 75 && n < NN){
                float mu = stats_rd[m]*(1.0f/NN);
                float var = stats_rd[75+m]*(1.0f/NN) - mu*mu;
                float inv = rsqrtf(var + 1e-5f);
                v = (hc[(size_t)n*75 + m] - mu)*inv*bng[lp*75+m] + bnb[lp*75+m];
                v = v > 0.f ? v : 0.f;
                if (blockIdx.y == 0) h[(size_t)n*75 + m] = v;
            }
            s_h[idx] = v;
        }
    }

    for (int half = 0; half < 2; half++){
        int base_c = blockIdx.y*128 + half*64;
        if (half){
            __syncthreads();   // all reads of s_w (half 0) complete
        }
        // stage W tile: k-major, wave lanes cover 64 consecutive cols -> coalesced
        for (int idx = tid; idx < 76*64; idx += 256){
            int k = idx >> 6, c = idx & 63;
            int col = base_c + c;
            float v = 0.f;
            if (k < 75 && col < 750){
                int cc2 = col < 375 ? col : col - 375;
                int t = cc2/75, f = cc2 - t*75;
                int ro = col < 375 ? 0 : 75;
                v = preW[(((size_t)(l*NT + t))*225 + ro + k)*75 + f];
            }
            s_w[idx] = v;
        }
        __syncthreads();

        float acc[4][4] = {};
        const float* hrow = s_h + (ty*4)*76;
        const float* wrow = s_w + tx*4;
        for (int k4 = 0; k4 < 76; k4 += 4){
            float4 hv[4], wv[4];
            #pragma unroll
            for (int r = 0; r < 4; r++)
                hv[r] = *(const float4*)(hrow + r*76 + k4);
            #pragma unroll
            for (int kk = 0; kk < 4; kk++)
                wv[kk] = *(const float4*)(wrow + (k4+kk)*64);
            #pragma unroll
            for (int r = 0; r < 4; r++){
                float h0 = hv[r].x, h1 = hv[r].y, h2 = hv[r].z, h3 = hv[r].w;
                acc[r][0] += h0*wv[0].x + h1*wv[1].x + h2*wv[2].x + h3*wv[3].x;
                acc[r][1] += h0*wv[0].y + h1*wv[1].y + h2*wv[2].y + h3*wv[3].y;
                acc[r][2] += h0*wv[0].z + h1*wv[1].z + h2*wv[2].z + h3*wv[3].z;
                acc[r][3] += h0*wv[0].w + h1*wv[1].w + h2*wv[2].w + h3*wv[3].w;
            }
        }

        #pragma unroll
        for (int r = 0; r < 4; r++){
            int n = base_n + ty*4 + r;
            if (n >= NN) continue;
            #pragma unroll
            for (int cc = 0; cc < 4; cc++){
                int c = base_c + tx*4 + cc;
                if (c >= 750) continue;
                __hip_bfloat16 v = __float2bfloat16(acc[r][cc]);
                if (c < 375) P[(size_t)n*375 + c] = v;
                else         Q[(size_t)n*375 + (c - 375)] = v;
            }
        }
    }
}

// grid (6, NN), block 64. bf16 Q gather; edge loop unrolled x8.
// R20: block (0,0) additionally zeros the BN-stats buffer for this layer
// (runs before k_lin's atomicAdds via stream ordering).
__global__ __launch_bounds__(64) void k_agg(const __hip_bfloat16* __restrict__ P,
        const __hip_bfloat16* __restrict__ Q, const float* __restrict__ Rlut,
        const int* __restrict__ eoff, const int* __restrict__ esrc,
        const int* __restrict__ ecombo, const float* __restrict__ invdeg,
        __hip_bfloat16* __restrict__ agg, float* __restrict__ stats_zero){
    int n = blockIdx.y;
    int j = blockIdx.x*64 + threadIdx.x;
    if (blockIdx.x == 0 && n == 0){
        for (int i = threadIdx.x; i < 150; i += 64) stats_zero[i] = 0.f;
    }
    if (j >= 375) return;
    int lo = eoff[n], hi = eoff[n+1];
    float p = bf2f(P[(size_t)n*375 + j]);
    float sum = 0.f, sq = 0.f, mn = 3.4e38f, mx = -3.4e38f;
    int e = lo;
    for (; e + 8 <= hi; e += 8){
        int s0 = esrc[e],   s1 = esrc[e+1], s2 = esrc[e+2], s3 = esrc[e+3];
        int s4 = esrc[e+4], s5 = esrc[e+5], s6 = esrc[e+6], s7 = esrc[e+7];
        int c0 = ecombo[e],   c1 = ecombo[e+1], c2 = ecombo[e+2], c3 = ecombo[e+3];
        int c4 = ecombo[e+4], c5 = ecombo[e+5], c6 = ecombo[e+6], c7 = ecombo[e+7];
        float q0 = bf2f(Q[(size_t)s0*375 + j]);
        float q1 = bf2f(Q[(size_t)s1*375 + j]);
        float q2 = bf2f(Q[(size_t)s2*375 + j]);
        float q3 = bf2f(Q[(size_t)s3*375 + j]);
        float q4 = bf2f(Q[(size_t)s4*375 + j]);
        float q5 = bf2f(Q[(size_t)s5*375 + j]);
        float q6 = bf2f(Q[(size_t)s6*375 + j]);
        float q7 = bf2f(Q[(size_t)s7*375 + j]);
        float r0 = Rlut[c0*375 + j], r1 = Rlut[c1*375 + j];
        float r2 = Rlut[c2*375 + j], r3 = Rlut[c3*375 + j];
        float r4 = Rlut[c4*375 + j], r5 = Rlut[c5*375 + j];
        float r6 = Rlut[c6*375 + j], r7 = Rlut[c7*375 + j];
        float m0 = p + q0 + r0, m1 = p + q1 + r1;
        float m2 = p + q2 + r2, m3 = p + q3 + r3;
        float m4 = p + q4 + r4, m5 = p + q5 + r5;
        float m6 = p + q6 + r6, m7 = p + q7 + r7;
        sum += (m0 + m1 + m2 + m3) + (m4 + m5 + m6 + m7);
        sq  += (m0*m0 + m1*m1 + m2*m2 + m3*m3) + (m4*m4 + m5*m5 + m6*m6 + m7*m7);
        mn = fminf(mn, fminf(fminf(fminf(m0,m1), fminf(m2,m3)),
                             fminf(fminf(m4,m5), fminf(m6,m7))));
        mx = fmaxf(mx, fmaxf(fmaxf(fmaxf(m0,m1), fmaxf(m2,m3)),
                             fmaxf(fmaxf(m4,m5), fmaxf(m6,m7))));
    }
    for (; e < hi; e++){
        int s = esrc[e], cm = ecombo[e];
        float m = p + bf2f(Q[(size_t)s*375 + j]) + Rlut[cm*375 + j];
        sum += m; sq += m*m;
        mn = fminf(mn, m); mx = fmaxf(mx, m);
    }
    float id = invdeg[n];
    bool has = hi > lo;
    float mean = sum*id;
    float msq  = sq*id;
    float var = msq - mean*mean; var = var > 0.f ? var : 0.f;
    float sd = sqrtf(var + 1e-5f);
    float mnv = has ? mn : 0.f;
    float mxv = has ? mx : 0.f;
    int t = j/75, f = j - 75*t;
    __hip_bfloat16* a = agg + ((size_t)n*NT + t)*300;
    a[f]      = __float2bfloat16(mean);
    a[75+f]   = __float2bfloat16(mnv);
    a[150+f]  = __float2bfloat16(mxv);
    a[225+f]  = __float2bfloat16(sd);
}

// post einsum, barrier-free; bf16 partials. grid (79, 5, 7).
// R19: 128-node tile: LDS 22.9 KB, 2765 blocks for smoother CU packing.
// R17 LDS staging retained: agg tile stride 52 ushorts, conflict-free.
#define KB2 50
__global__ __launch_bounds__(256, 6) void k_post(const float* __restrict__ h,
        const __hip_bfloat16* __restrict__ agg, const float* __restrict__ postW,
        const float* __restrict__ postb, const float* __restrict__ amp,
        const float* __restrict__ att, int l, __hip_bfloat16* __restrict__ postbase){
    __shared__ float s_w[3*KB2*16];              // 9.6 KB (z0 uses first 75*16=1200)
    __shared__ unsigned short s_a[128*52];       // 13.3 KB agg tile
    int t = blockIdx.y;
    int z = blockIdx.z;
    int nbase = blockIdx.x*128;
    int tid = threadIdx.x;
    int fg  = (tid & 3)*4;
    int sub = tid >> 2;
    const float* Wt = postW + ((size_t)(l*NT + t))*975*15;

    if (z == 0){
        for (int idx = tid; idx < 75*16; idx += 256){
            int c = idx >> 4, f = idx & 15;
            s_w[idx] = (f < 15) ? Wt[c*15 + f] : 0.f;
        }
        __syncthreads();
        float a1[2][4] = {};
        const float* hrow[2];
        #pragma unroll
        for (int j = 0; j < 2; j++){
            int n = nbase + sub + 64*j;
            hrow[j] = h + (size_t)(n < NN ? n : 0)*75;
        }
        #pragma unroll 3
        for (int k = 0; k < 75; k++){
            const float4 w1 = *(const float4*)&s_w[k*16 + fg];
            #pragma unroll
            for (int j = 0; j < 2; j++){
                float v = hrow[j][k];
                a1[j][0] += v*w1.x; a1[j][1] += v*w1.y;
                a1[j][2] += v*w1.z; a1[j][3] += v*w1.w;
            }
        }
        const float* pb = postb + (l*NT + t)*15;
        #pragma unroll
        for (int j = 0; j < 2; j++){
            int n = nbase + sub + 64*j;
            if (n >= NN) continue;
            __hip_bfloat16* dst = postbase + (size_t)n*75 + t*15;
            #pragma unroll
            for (int f = 0; f < 4; f++)
                if (fg + f < 15) dst[fg + f] = __float2bfloat16(a1[j][f] + pb[fg + f]);
        }
        return;
    }

    int kbeg = (z-1)*KB2;
    // stage weights
    for (int idx = tid; idx < 3*KB2*16; idx += 256){
        int vrow = idx / (KB2*16);
        int rem = idx - vrow*(KB2*16);
        int c = rem >> 4, f = rem & 15;
        s_w[idx] = (f < 15) ? Wt[(75 + vrow*300 + kbeg + c)*15 + f] : 0.f;
    }
    // stage agg tile: node i's 50 bf16 slice = 25 dwords, contiguous 100B runs
    {
        const unsigned short* asrc = (const unsigned short*)agg;
        for (int idx = tid; idx < 128*25; idx += 256){
            int i = idx/25, w = idx - 25*i;
            int n = nbase + i;
            unsigned int u = 0;
            if (n < NN)
                u = *(const unsigned int*)(asrc + (size_t)n*1500 + t*300 + kbeg + 2*w);
            *(unsigned int*)&s_a[i*52 + 2*w] = u;
        }
    }
    __syncthreads();

    float a1[2][4] = {}, a2[2][4] = {}, a3[2][4] = {};
    const unsigned short* ap0 = s_a + sub*52;
    #pragma unroll 2
    for (int k4 = 0; k4 < 48; k4 += 4){
        uv2 ua[2];
        #pragma unroll
        for (int j = 0; j < 2; j++)
            ua[j] = *(const uv2*)(ap0 + j*(64*52) + k4);
        #pragma unroll
        for (int kk = 0; kk < 4; kk++){
            int k = k4 + kk;
            const float4 w1 = *(const float4*)&s_w[k*16 + fg];
            const float4 w2 = *(const float4*)&s_w[(KB2 + k)*16 + fg];
            const float4 w3 = *(const float4*)&s_w[(2*KB2 + k)*16 + fg];
            #pragma unroll
            for (int j = 0; j < 2; j++){
                unsigned int bits = (kk < 2) ? ua[j].x : ua[j].y;
                float v = __uint_as_float((kk & 1) ? (bits & 0xffff0000u)
                                                   : (bits << 16));
                a1[j][0] += v*w1.x; a1[j][1] += v*w1.y;
                a1[j][2] += v*w1.z; a1[j][3] += v*w1.w;
                a2[j][0] += v*w2.x; a2[j][1] += v*w2.y;
                a2[j][2] += v*w2.z; a2[j][3] += v*w2.w;
                a3[j][0] += v*w3.x; a3[j][1] += v*w3.y;
                a3[j][2] += v*w3.z; a3[j][3] += v*w3.w;
            }
        }
    }
    // tail k = 48, 49 (one dword per row)
    {
        unsigned int ut[2];
        #pragma unroll
        for (int j = 0; j < 2; j++)
            ut[j] = *(const unsigned int*)(ap0 + j*(64*52) + 48);
        #pragma unroll
        for (int kk = 0; kk < 2; kk++){
            int k = 48 + kk;
            const float4 w1 = *(const float4*)&s_w[k*16 + fg];
            const float4 w2 = *(const float4*)&s_w[(KB2 + k)*16 + fg];
            const float4 w3 = *(const float4*)&s_w[(2*KB2 + k)*16 + fg];
            #pragma unroll
            for (int j = 0; j < 2; j++){
                float v = __uint_as_float((kk & 1) ? (ut[j] & 0xffff0000u)
                                                   : (ut[j] << 16));
                a1[j][0] += v*w1.x; a1[j][1] += v*w1.y;
                a1[j][2] += v*w1.z; a1[j][3] += v*w1.w;
                a2[j][0] += v*w2.x; a2[j][1] += v*w2.y;
                a2[j][2] += v*w2.z; a2[j][3] += v*w2.w;
                a3[j][0] += v*w3.x; a3[j][1] += v*w3.y;
                a3[j][2] += v*w3.z; a3[j][3] += v*w3.w;
            }
        }
    }
    __hip_bfloat16* postv = postbase + (size_t)z*750000;
    #pragma unroll
    for (int j = 0; j < 2; j++){
        int n = nbase + sub + 64*j;
        if (n >= NN) continue;
        float am = amp[n], at = att[n];
        __hip_bfloat16* dst = postv + (size_t)n*75 + t*15;
        #pragma unroll
        for (int f = 0; f < 4; f++)
            if (fg + f < 15)
                dst[fg + f] = __float2bfloat16(a1[j][f] + am*a2[j][f] + at*a3[j][f]);
    }
}

// hc = (Σz postz) @ lin_W[l] + lin_b[l]; fused BN-stat reduction into buffer l&1.
// R25: reverted to the R4 geometry (32 nodes x 313 blocks) — R8's 16x625
// split was a measured ~14 us total regression (doubled linW staging).
__global__ __launch_bounds__(256) void k_lin(const __hip_bfloat16* __restrict__ postbase,
        const float* __restrict__ linW, const float* __restrict__ linb,
        int l, float* __restrict__ hc, float* __restrict__ stats_all){
    __shared__ float p_l[32*75];
    __shared__ float w_l[75*75];
    __shared__ float hc_l[32*75];
    int tid = threadIdx.x;
    int base = blockIdx.x*32;
    for (int i = tid; i < 75*75; i += 256) w_l[i] = linW[(size_t)l*5625 + i];
    for (int i = tid; i < 32*75; i += 256){
        int n = base + i/75;
        size_t idx = (size_t)base*75 + i;
        float v = 0.f;
        if (n < NN){
            #pragma unroll
            for (int z = 0; z < 7; z++) v += bf2f(postbase[idx + (size_t)z*750000]);
        }
        p_l[i] = v;
    }
    __syncthreads();
    for (int task = tid; task < 2400; task += 256){
        int i = task/75, o = task - 75*i;
        float s = linb[l*75 + o];
        const float* pl = p_l + i*75;
        #pragma unroll 5
        for (int j = 0; j < 75; j++) s += pl[j]*w_l[j*75 + o];
        hc_l[task] = s;
        if (base + i < NN) hc[(size_t)(base+i)*75 + o] = s;
    }
    __syncthreads();
    if (tid < 75){
        float* stats_wr = stats_all + (l & 1)*192;
        int nv = NN - base; if (nv > 32) nv = 32;
        float s1 = 0.f, s2 = 0.f;
        for (int i = 0; i < nv; i++){
            float v = hc_l[i*75 + tid];
            s1 += v; s2 += v*v;
        }
        atomicAdd(&stats_wr[tid], s1);
        atomicAdd(&stats_wr[75+tid], s2);
    }
}

// final BN apply (only after last layer; earlier layers fused into k_pq)
__global__ void k_bnapply(const float* __restrict__ hc, const float* __restrict__ stats,
        const float* __restrict__ bng, const float* __restrict__ bnb, int l,
        float* __restrict__ h){
    int idx = blockIdx.x*256 + threadIdx.x;
    if (idx >= NN*75) return;
    int col = idx % 75;
    float mu = stats[col]*(1.0f/NN);
    float var = stats[75+col]*(1.0f/NN) - mu*mu;
    float inv = rsqrtf(var + 1e-5f);
    float v = (hc[idx] - mu)*inv*bng[l*75+col] + bnb[l*75+col];
    h[idx] = v > 0.f ? v : 0.f;
}

__global__ __launch_bounds__(256) void k_pool(const float* __restrict__ h,
        const int* __restrict__ batch, float* __restrict__ gpool){
    int g = blockIdx.x, tid = threadIdx.x;
    int lo = 0, hi = NN;
    while (lo < hi){ int mid = (lo+hi)>>1; if (batch[mid] < g) lo = mid+1; else hi = mid; }
    int start = lo;
    lo = start; hi = NN;
    while (lo < hi){ int mid = (lo+hi)>>1; if (batch[mid] < g+1) lo = mid+1; else hi = mid; }
    int end = lo;
    __shared__ float red[225];
    if (tid < 225){
        int col = tid % 75, rep = tid / 75;
        float acc = 0.f;
        for (int i = start + rep; i < end; i += 3) acc += h[(size_t)i*75 + col];
        red[tid] = acc;
    }
    __syncthreads();
    if (tid < 75) gpool[g*75 + tid] = red[tid] + red[75+tid] + red[150+tid];
}

// 8 blocks x 8 graphs; weights in LDS, phase-parallel
__global__ __launch_bounds__(256) void k_mlp(const float* __restrict__ gpool,
        const float* __restrict__ W1, const float* __restrict__ b1,
        const float* __restrict__ W2, const float* __restrict__ b2,
        const float* __restrict__ W3, const float* __restrict__ b3,
        float* __restrict__ out){
    __shared__ float w1[75*50];
    __shared__ float w2[50*25];
    __shared__ float gp[8*75];
    __shared__ float t1[8*50];
    __shared__ float t2[8*25];
    int tid = threadIdx.x;
    int gbase = blockIdx.x*8;
    for (int i = tid; i < 75*50; i += 256) w1[i] = W1[i];
    for (int i = tid; i < 50*25; i += 256) w2[i] = W2[i];
    for (int i = tid; i < 8*75; i += 256) gp[i] = gpool[gbase*75 + i];
    __syncthreads();
    for (int task = tid; task < 8*50; task += 256){
        int g = task/50, j = task - 50*g;
        float s = b1[j];
        const float* gv = gp + g*75;
        #pragma unroll 5
        for (int k = 0; k < 75; k++) s += gv[k]*w1[k*50+j];
        t1[task] = s > 0.f ? s : 0.f;
    }
    __syncthreads();
    for (int task = tid; task < 8*25; task += 256){
        int g = task/25, j = task - 25*g;
        float s = b2[j];
        const float* tv = t1 + g*50;
        #pragma unroll 5
        for (int k = 0; k < 50; k++) s += tv[k]*w2[k*25+j];
        t2[task] = s > 0.f ? s : 0.f;
    }
    __syncthreads();
    if (tid < 8){
        float s = b3[0];
        const float* tv = t2 + tid*25;
        #pragma unroll
        for (int k = 0; k < 25; k++) s += tv[k]*W3[k];
        out[gbase + tid] = s;
    }
}

extern "C" void kernel_launch(void* const* d_in, const int* in_sizes, int n_in,
                              void* d_out, int out_size, void* d_ws, size_t ws_size,
                              hipStream_t stream){
    const int* x          = (const int*)d_in[0];
    const int* edge_index = (const int*)d_in[1];
    const int* edge_attr  = (const int*)d_in[2];
    const int* batch      = (const int*)d_in[3];
    const float* node_emb = (const float*)d_in[4];
    const float* edge_emb = (const float*)d_in[5];
    const float* pre_lin_W= (const float*)d_in[6];
    const float* pre_lin_b= (const float*)d_in[7];
    const float* encW     = (const float*)d_in[8];
    const float* encb     = (const float*)d_in[9];
    const float* preW     = (const float*)d_in[10];
    const float* preb     = (const float*)d_in[11];
    const float* postW    = (const float*)d_in[12];
    const float* postb    = (const float*)d_in[13];
    const float* linW     = (const float*)d_in[14];
    const float* linb     = (const float*)d_in[15];
    const float* bng      = (const float*)d_in[16];
    const float* bnb      = (const float*)d_in[17];
    const float* mlpW1    = (const float*)d_in[18];
    const float* mlpb1    = (const float*)d_in[19];
    const float* mlpW2    = (const float*)d_in[20];
    const float* mlpb2    = (const float*)d_in[21];
    const float* mlpW3    = (const float*)d_in[22];
    const float* mlpb3    = (const float*)d_in[23];

    float* ws = (float*)d_ws;
    float* h      = ws + OFF_H;
    float* hc     = ws + OFF_HC;
    __hip_bfloat16* P = (__hip_bfloat16*)(ws + OFF_P);
    __hip_bfloat16* Q = (__hip_bfloat16*)(ws + OFF_Q);
    __hip_bfloat16* agg = (__hip_bfloat16*)(ws + OFF_AGG);
    float* rlut4  = ws + OFF_RLUT4;
    float* invdeg = ws + OFF_INVDEG;
    float* amp    = ws + OFF_AMP;
    float* att    = ws + OFF_ATT;
    float* stats  = ws + OFF_STATS;   // 2 x 192 ping-pong
    float* gpool  = ws + OFF_GPOOL;
    __hip_bfloat16* postbase = (__hip_bfloat16*)(ws + OFF_P);  // bf16 partials z=0..6
    int* iw     = (int*)(ws + OFF_INT);
    int* cnt    = iw;
    int* eoff   = cnt + NN;        // NN+1
    int* cursor = eoff + NN + 2;
    int* esrc   = cursor + NN;
    int* ecombo = esrc + NE;

    k_zero_cnt<<<40, 256, 0, stream>>>(cnt);
    k_rlut4<<<dim3(5, 4), 384, 0, stream>>>(preW, preb, edge_emb, encW, encb, rlut4);
    k_h0<<<640, 256, 0, stream>>>(x, node_emb, pre_lin_W, pre_lin_b, h);
    k_hist<<<625, 256, 0, stream>>>(edge_index, cnt);
    k_scan<<<1, 1024, 0, stream>>>(cnt, eoff, invdeg, amp, att, cursor);
    k_scatter<<<625, 256, 0, stream>>>(edge_index, edge_attr, cursor, esrc, ecombo);

    for (int l = 0; l < NL; l++){
        k_pq<<<dim3(157, 6), 256, 0, stream>>>(h, hc, bng, bnb, preW, l, P, Q, stats);
        k_agg<<<dim3(6, NN), 64, 0, stream>>>(P, Q, rlut4 + (size_t)l*6000,
                                              eoff, esrc, ecombo, invdeg, agg,
                                              stats + (l & 1)*192);
        k_post<<<dim3(79, 5, 7), 256, 0, stream>>>(h, agg, postW, postb, amp, att, l, postbase);
        k_lin<<<313, 256, 0, stream>>>(postbase, linW, linb, l, hc, stats);
    }

    // final BN (layer 3) -> h, then pool + MLP
    k_bnapply<<<2930, 256, 0, stream>>>(hc, stats + ((NL-1)&1)*192, bng, bnb, NL-1, h);
    k_pool<<<NG, 256, 0, stream>>>(h, batch, gpool);
    k_mlp<<<8, 256, 0, stream>>>(gpool, mlpW1, mlpb1, mlpW2, mlpb2, mlpW3, mlpb3, (float*)d_out);
}